// Round 5
// baseline (1209.592 us; speedup 1.0000x reference)
//
#include <hip/hip_runtime.h>
#include <math.h>

#define N_NODES 4096
#define DIM 384
#define QKVD 1152
#define N_EDGES 131072
#define N_HEADS 8
#define DH 48
#define N_LAYERS 3

typedef short v4s __attribute__((ext_vector_type(4)));
typedef short v8s __attribute__((ext_vector_type(8)));
typedef float v4f __attribute__((ext_vector_type(4)));

#define MFMA32(A, B, C) __builtin_amdgcn_mfma_f32_16x16x32_bf16(A, B, C, 0, 0, 0)
#define MFMA16(A, B, C) __builtin_amdgcn_mfma_f32_16x16x16bf16_1k(A, B, C, 0, 0, 0)
#define EXP2F(x) __builtin_exp2f(x)

// ======================= CSR build (counting sort by dst) =======================

__global__ void zero_counts_kernel(int* counts, int* cursor) {
  int i = blockIdx.x * blockDim.x + threadIdx.x;
  if (i < N_NODES) { counts[i] = 0; cursor[i] = 0; }
}

__global__ void count_kernel(const int* __restrict__ dst, int* counts) {
  int e = blockIdx.x * blockDim.x + threadIdx.x;
  if (e < N_EDGES) atomicAdd(&counts[dst[e]], 1);
}

__global__ __launch_bounds__(1024) void scan_kernel(const int* __restrict__ counts,
                                                    int* __restrict__ offsets) {
  __shared__ int s[1024];
  int t = threadIdx.x;
  int base = t * 4;
  int c[4];
  int sum = 0;
  #pragma unroll
  for (int i = 0; i < 4; i++) { c[i] = counts[base + i]; sum += c[i]; }
  s[t] = sum;
  __syncthreads();
  for (int off = 1; off < 1024; off <<= 1) {
    int v = (t >= off) ? s[t - off] : 0;
    __syncthreads();
    s[t] += v;
    __syncthreads();
  }
  int excl = s[t] - sum;
  #pragma unroll
  for (int i = 0; i < 4; i++) { offsets[base + i] = excl; excl += c[i]; }
  if (t == 1023) offsets[N_NODES] = s[1023];
}

__global__ void scatter_kernel(const int* __restrict__ dst, const int* __restrict__ src,
                               const int* __restrict__ offsets, int* cursor,
                               int* __restrict__ ssrc) {
  int e = blockIdx.x * blockDim.x + threadIdx.x;
  if (e < N_EDGES) {
    int d = dst[e];
    int pos = atomicAdd(&cursor[d], 1);
    ssrc[offsets[d] + pos] = src[e];
  }
}

// ======================= bf16 split helpers =======================

__device__ __forceinline__ void bsplit(float v, ushort& hi, ushort& lo) {
  unsigned b = __float_as_uint(v);
  unsigned hb = b & 0xFFFF0000u;
  hi = (ushort)(b >> 16);
  float r = v - __uint_as_float(hb);
  lo = (ushort)(__float_as_uint(r) >> 16);
}

__device__ __forceinline__ void psplit2(float a, float b, unsigned& hi, unsigned& lo) {
  hi = __builtin_amdgcn_perm(__float_as_uint(b), __float_as_uint(a), 0x07060302u);
  float ra = a - __uint_as_float(hi << 16);
  float rb = b - __uint_as_float(hi & 0xFFFF0000u);
  lo = __builtin_amdgcn_perm(__float_as_uint(rb), __float_as_uint(ra), 0x07060302u);
}

// ======================= neighbor aggregation (+ split epilogue) =================

__global__ __launch_bounds__(128) void aggregate_kernel(const float* __restrict__ h,
    const int* __restrict__ ssrc, const int* __restrict__ offsets,
    ushort* __restrict__ aggH, ushort* __restrict__ aggL) {
  int i = blockIdx.x;
  int t = threadIdx.x;
  int e0 = offsets[i], e1 = offsets[i + 1];
  float a0 = 0.f, a1 = 0.f, a2 = 0.f;
  for (int e = e0; e < e1; e++) {
    const float* row = h + (size_t)ssrc[e] * DIM;
    a0 += row[t];
    a1 += row[t + 128];
    a2 += row[t + 256];
  }
  ushort h0, l0, h1, l1, h2, l2;
  bsplit(a0, h0, l0); bsplit(a1, h1, l1); bsplit(a2, h2, l2);
  size_t base = (size_t)i * DIM;
  aggH[base + t] = h0;       aggL[base + t] = l0;
  aggH[base + t + 128] = h1; aggL[base + t + 128] = l1;
  aggH[base + t + 256] = h2; aggL[base + t + 256] = l2;
}

// ======================= weight prep kernels =======================

__global__ void transpose_split_kernel(const float* __restrict__ Wc,
    ushort* __restrict__ wctH, ushort* __restrict__ wctL) {
  __shared__ float s[32][33];
  const int l = blockIdx.z;
  const float* W = Wc + (size_t)l * DIM * DIM;
  int tx = threadIdx.x, ty = threadIdx.y;
  s[ty][tx] = W[(size_t)(blockIdx.y * 32 + ty) * DIM + blockIdx.x * 32 + tx];
  __syncthreads();
  float v = s[tx][ty];
  ushort hi, lo;
  bsplit(v, hi, lo);
  size_t off = (size_t)l * DIM * DIM + (size_t)(blockIdx.x * 32 + ty) * DIM + blockIdx.y * 32 + tx;
  wctH[off] = hi;
  wctL[off] = lo;
}

__global__ void split_kernel(const float* __restrict__ src,
    ushort* __restrict__ hi, ushort* __restrict__ lo, int n) {
  int i = (blockIdx.x * 256 + threadIdx.x) * 4;
  if (i >= n) return;
  float4 v = *(const float4*)(src + i);
  ushort4 H, L;
  bsplit(v.x, H.x, L.x); bsplit(v.y, H.y, L.y);
  bsplit(v.z, H.z, L.z); bsplit(v.w, H.w, L.w);
  *(ushort4*)(hi + i) = H;
  *(ushort4*)(lo + i) = L;
}

// wibc[l][i] = dot(Wi[i,:], b_conv[l,:])
__global__ __launch_bounds__(256) void wibc_kernel(const float* __restrict__ Wi,
    const float* __restrict__ bconv, float* __restrict__ wibc) {
  int gw = (blockIdx.x * 256 + threadIdx.x) >> 6;
  int lane = threadIdx.x & 63;
  if (gw >= 3 * QKVD) return;
  int l = gw / QKVD, i = gw - l * QKVD;
  const float* w = Wi + (size_t)i * DIM;
  const float* b = bconv + (size_t)l * DIM;
  float s = 0.f;
  #pragma unroll
  for (int c = 0; c < 6; c++) s += w[lane + c * 64] * b[lane + c * 64];
  #pragma unroll
  for (int off = 32; off >= 1; off >>= 1) s += __shfl_xor(s, off, 64);
  if (lane == 0) wibc[gw] = s;
}

// ======================= split-bf16 MFMA GEMM core ==============================

template<int K>
__device__ __forceinline__ void mfma_core(
    const ushort* __restrict__ Ah, const ushort* __restrict__ Al,
    const ushort* __restrict__ Bh, const ushort* __restrict__ Bl,
    int aRow0, int bRow0, int li, int quad, v4f acc[4][4])
{
  for (int k0 = 0; k0 < K; k0 += 32) {
    v8s Afh[4], Afl[4], Bfh[4], Bfl[4];
    #pragma unroll
    for (int t = 0; t < 4; t++) {
      size_t ao = (size_t)(aRow0 + t * 16 + li) * K + k0 + quad * 8;
      size_t bo = (size_t)(bRow0 + t * 16 + li) * K + k0 + quad * 8;
      Afh[t] = *(const v8s*)(Ah + ao);
      Afl[t] = *(const v8s*)(Al + ao);
      Bfh[t] = *(const v8s*)(Bh + bo);
      Bfl[t] = *(const v8s*)(Bl + bo);
    }
    #pragma unroll
    for (int mt = 0; mt < 4; mt++)
      #pragma unroll
      for (int nt = 0; nt < 4; nt++) {
        v4f a = acc[mt][nt];
        a = MFMA32(Afh[mt], Bfh[nt], a);
        a = MFMA32(Afl[mt], Bfh[nt], a);
        a = MFMA32(Afh[mt], Bfl[nt], a);
        acc[mt][nt] = a;
      }
  }
}

// --- weight-prep GEMM: Wf[l] = Wi @ Wct[l] ---
__global__ __launch_bounds__(256) void wprep_gemm(
    const ushort* __restrict__ wiH, const ushort* __restrict__ wiL,
    const ushort* __restrict__ wctH, const ushort* __restrict__ wctL,
    ushort* __restrict__ wfH, ushort* __restrict__ wfL)
{
  const int l = blockIdx.z;
  const ushort* Bh = wctH + (size_t)l * DIM * DIM;
  const ushort* Bl = wctL + (size_t)l * DIM * DIM;
  ushort* oH = wfH + (size_t)l * QKVD * DIM;
  ushort* oL = wfL + (size_t)l * QKVD * DIM;
  const int tid = threadIdx.x;
  const int lane = tid & 63, li = lane & 15, quad = lane >> 4;
  const int w = tid >> 6, wm = w & 1, wn = w >> 1;
  const int aRow0 = blockIdx.x * 128 + wm * 64;
  const int bRow0 = blockIdx.y * 128 + wn * 64;
  v4f acc[4][4] = {};
  mfma_core<DIM>(wiH, wiL, Bh, Bl, aRow0, bRow0, li, quad, acc);
  #pragma unroll
  for (int mt = 0; mt < 4; mt++) {
    int i0 = aRow0 + mt * 16 + quad * 4;
    #pragma unroll
    for (int nt = 0; nt < 4; nt++) {
      int j = bRow0 + nt * 16 + li;
      #pragma unroll
      for (int r = 0; r < 4; r++) {
        ushort hi, lo;
        bsplit(acc[mt][nt][r], hi, lo);
        oH[(size_t)(i0 + r) * DIM + j] = hi;
        oL[(size_t)(i0 + r) * DIM + j] = lo;
      }
    }
  }
}

// --- fused qkv GEMM ---
__global__ __launch_bounds__(256) void qkv_gemm(
    const ushort* __restrict__ wfH, const ushort* __restrict__ wfL,
    const ushort* __restrict__ aggH, const ushort* __restrict__ aggL,
    const float* __restrict__ wibc_l, const float* __restrict__ b_in,
    const int* __restrict__ deg,
    ushort* __restrict__ qhi, ushort* __restrict__ qlo,
    ushort* __restrict__ khi, ushort* __restrict__ klo,
    ushort* __restrict__ vthi, ushort* __restrict__ vtlo)
{
  const int tid = threadIdx.x;
  const int lane = tid & 63, li = lane & 15, quad = lane >> 4;
  const int w = tid >> 6, wm = w & 1, wn = w >> 1;
  const int aRow0 = blockIdx.x * 128 + wm * 64;   // channel base
  const int bRow0 = blockIdx.y * 128 + wn * 64;   // node base
  v4f acc[4][4] = {};
  mfma_core<DIM>(wfH, wfL, aggH, aggL, aRow0, bRow0, li, quad, acc);

  const float cq = 0.20823507f;  // log2(e)/sqrt(48)
  int node[4]; float degf[4];
  #pragma unroll
  for (int nt = 0; nt < 4; nt++) {
    node[nt] = bRow0 + nt * 16 + li;
    degf[nt] = (float)deg[node[nt]];
  }
  #pragma unroll
  for (int mt = 0; mt < 4; mt++) {
    const int c0 = aRow0 + mt * 16 + quad * 4;
    const int part = c0 / DIM;
    const int cm = c0 - part * DIM;
    const int hd = cm / DH;
    const int d0 = cm - hd * DH;
    float wb[4], bb[4];
    #pragma unroll
    for (int r = 0; r < 4; r++) { wb[r] = wibc_l[c0 + r]; bb[r] = b_in[c0 + r]; }
    #pragma unroll
    for (int nt = 0; nt < 4; nt++) {
      float v0 = acc[mt][nt][0] + degf[nt] * wb[0] + bb[0];
      float v1 = acc[mt][nt][1] + degf[nt] * wb[1] + bb[1];
      float v2 = acc[mt][nt][2] + degf[nt] * wb[2] + bb[2];
      float v3 = acc[mt][nt][3] + degf[nt] * wb[3] + bb[3];
      if (part == 0) {
        v0 *= cq; v1 *= cq; v2 *= cq; v3 *= cq;
        ushort4 H, L;
        bsplit(v0, H.x, L.x); bsplit(v1, H.y, L.y);
        bsplit(v2, H.z, L.z); bsplit(v3, H.w, L.w);
        size_t off = ((size_t)hd * N_NODES + node[nt]) * DH + d0;
        *(ushort4*)(qhi + off) = H;
        *(ushort4*)(qlo + off) = L;
      } else if (part == 1) {
        ushort4 H, L;
        bsplit(v0, H.x, L.x); bsplit(v1, H.y, L.y);
        bsplit(v2, H.z, L.z); bsplit(v3, H.w, L.w);
        size_t off = ((size_t)hd * N_NODES + node[nt]) * DH + d0;
        *(ushort4*)(khi + off) = H;
        *(ushort4*)(klo + off) = L;
      } else {
        float vv[4] = {v0, v1, v2, v3};
        #pragma unroll
        for (int r = 0; r < 4; r++) {
          ushort hi, lo;
          bsplit(vv[r], hi, lo);
          size_t off = ((size_t)hd * DH + d0 + r) * N_NODES + node[nt];
          vthi[off] = hi;
          vtlo[off] = lo;
        }
      }
    }
  }
}

// --- attn-out GEMM: h = relu(ao @ Wao^T + b_ao + h) ---
__global__ __launch_bounds__(256) void outproj_gemm(
    const ushort* __restrict__ aoH, const ushort* __restrict__ aoL,
    const ushort* __restrict__ waoH, const ushort* __restrict__ waoL,
    const float* __restrict__ b_ao, float* __restrict__ h)
{
  const int tid = threadIdx.x;
  const int lane = tid & 63, li = lane & 15, quad = lane >> 4;
  const int w = tid >> 6, wm = w & 1, wn = w >> 1;
  const int aRow0 = blockIdx.x * 128 + wm * 64;   // node base
  const int bRow0 = blockIdx.y * 128 + wn * 64;   // channel base
  v4f acc[4][4] = {};
  mfma_core<DIM>(aoH, aoL, waoH, waoL, aRow0, bRow0, li, quad, acc);
  #pragma unroll
  for (int mt = 0; mt < 4; mt++) {
    int m0 = aRow0 + mt * 16 + quad * 4;
    #pragma unroll
    for (int nt = 0; nt < 4; nt++) {
      int n = bRow0 + nt * 16 + li;
      float ba = b_ao[n];
      #pragma unroll
      for (int r = 0; r < 4; r++) {
        size_t off = (size_t)(m0 + r) * DIM + n;
        float v = acc[mt][nt][r] + ba + h[off];
        h[off] = fmaxf(v, 0.f);
      }
    }
  }
}

// ======================= MFMA flash attention (split-bf16, KV-split 2) ==========
// grid (H=8, N/64=64, 2 KV-halves), 256 thr = 4 waves. Wave w owns kcol slice
// [kb+16w, kb+16w+16). 64 Q-rows per block. Block writes unnormalized partial
// (O, m, l); attn_merge_kernel combines the two halves.
// head = blockIdx.x -> block id % 8 = head -> each head's K/V pinned to one XCD L2.

__global__ __launch_bounds__(256, 3) void attn_kernel(
    const ushort* __restrict__ qhi, const ushort* __restrict__ qlo,
    const ushort* __restrict__ khi, const ushort* __restrict__ klo,
    const ushort* __restrict__ vthi, const ushort* __restrict__ vtlo,
    float* __restrict__ Opart0, float* __restrict__ Opart1,
    float* __restrict__ mpart, float* __restrict__ lpart)
{
  const int head = blockIdx.x;
  const int qy = blockIdx.y;
  const int z = blockIdx.z;
  const int qBase = qy * 64;
  const int kb0 = z * (N_NODES / 2);
  const int tid = threadIdx.x;
  const int w = tid >> 6;
  const int lane = tid & 63;
  const int li = lane & 15, quad = lane >> 4;

  const size_t headQK = (size_t)head * N_NODES * DH;
  const size_t headV  = (size_t)head * DH * N_NODES;

  // resident Q fragments (4 q-tiles of 16 rows)
  v8s q0h[4], q0l[4];
  v4s q1h[4], q1l[4];
  #pragma unroll
  for (int qt = 0; qt < 4; qt++) {
    const ushort* qr = qhi + headQK + (size_t)(qBase + 16 * qt + li) * DH;
    const ushort* ql = qlo + headQK + (size_t)(qBase + 16 * qt + li) * DH;
    q0h[qt] = *(const v8s*)(qr + quad * 8);
    q0l[qt] = *(const v8s*)(ql + quad * 8);
    q1h[qt] = *(const v4s*)(qr + 32 + quad * 4);
    q1l[qt] = *(const v4s*)(ql + 32 + quad * 4);
  }

  v4f ot[3][4];
  #pragma unroll
  for (int mt = 0; mt < 3; mt++)
    #pragma unroll
    for (int qt = 0; qt < 4; qt++)
      ot[mt][qt] = (v4f){0.f, 0.f, 0.f, 0.f};
  float m2[4] = {-3.0e38f, -3.0e38f, -3.0e38f, -3.0e38f};
  float lsum[4] = {0.f, 0.f, 0.f, 0.f};

  const ushort* kh_p = khi + headQK + (size_t)(kb0 + 16 * w + li) * DH;
  const ushort* kl_p = klo + headQK + (size_t)(kb0 + 16 * w + li) * DH;
  const ushort* vh_p = vthi + headV + (size_t)li * N_NODES + kb0 + 16 * w + quad * 4;
  const ushort* vl_p = vtlo + headV + (size_t)li * N_NODES + kb0 + 16 * w + quad * 4;

  v8s nk0h = *(const v8s*)(kh_p + quad * 8);
  v8s nk0l = *(const v8s*)(kl_p + quad * 8);
  v4s nk1h = *(const v4s*)(kh_p + 32 + quad * 4);
  v4s nk1l = *(const v4s*)(kl_p + 32 + quad * 4);
  v4s nvh[3], nvl[3];
  #pragma unroll
  for (int mt = 0; mt < 3; mt++) {
    nvh[mt] = *(const v4s*)(vh_p + (size_t)mt * 16 * N_NODES);
    nvl[mt] = *(const v4s*)(vl_p + (size_t)mt * 16 * N_NODES);
  }

  for (int kb = kb0; kb < kb0 + N_NODES / 2; kb += 64) {
    v8s ck0h = nk0h, ck0l = nk0l;
    v4s ck1h = nk1h, ck1l = nk1l;
    v4s cvh[3], cvl[3];
    #pragma unroll
    for (int mt = 0; mt < 3; mt++) { cvh[mt] = nvh[mt]; cvl[mt] = nvl[mt]; }

    if (kb + 64 < kb0 + N_NODES / 2) {
      kh_p += 64 * DH; kl_p += 64 * DH; vh_p += 64; vl_p += 64;
      nk0h = *(const v8s*)(kh_p + quad * 8);
      nk0l = *(const v8s*)(kl_p + quad * 8);
      nk1h = *(const v4s*)(kh_p + 32 + quad * 4);
      nk1l = *(const v4s*)(kl_p + 32 + quad * 4);
      #pragma unroll
      for (int mt = 0; mt < 3; mt++) {
        nvh[mt] = *(const v4s*)(vh_p + (size_t)mt * 16 * N_NODES);
        nvl[mt] = *(const v4s*)(vl_p + (size_t)mt * 16 * N_NODES);
      }
    }

    // S^T = K·Q^T (log2-domain scores via pre-scaled q)
    v4f s[4];
    #pragma unroll
    for (int qt = 0; qt < 4; qt++) {
      v4f acc = (v4f){0.f, 0.f, 0.f, 0.f};
      acc = MFMA32(ck0h, q0h[qt], acc);
      acc = MFMA32(ck0l, q0h[qt], acc);
      acc = MFMA32(ck0h, q0l[qt], acc);
      acc = MFMA16(ck1h, q1h[qt], acc);
      acc = MFMA16(ck1l, q1h[qt], acc);
      acc = MFMA16(ck1h, q1l[qt], acc);
      s[qt] = acc;
    }

    // online softmax over this wave's 16 kcols
    v4s pH[4], pL[4];
    float al[4];
    #pragma unroll
    for (int qt = 0; qt < 4; qt++) {
      float mx = fmaxf(fmaxf(s[qt][0], s[qt][1]), fmaxf(s[qt][2], s[qt][3]));
      mx = fmaxf(mx, __shfl_xor(mx, 16, 64));
      mx = fmaxf(mx, __shfl_xor(mx, 32, 64));
      float mn = fmaxf(m2[qt], mx);
      float a = EXP2F(m2[qt] - mn);
      m2[qt] = mn;
      al[qt] = a;
      float p0 = EXP2F(s[qt][0] - mn);
      float p1 = EXP2F(s[qt][1] - mn);
      float p2 = EXP2F(s[qt][2] - mn);
      float p3 = EXP2F(s[qt][3] - mn);
      float rs = (p0 + p1) + (p2 + p3);
      rs += __shfl_xor(rs, 16, 64);
      rs += __shfl_xor(rs, 32, 64);
      lsum[qt] = lsum[qt] * a + rs;
      unsigned h0, l0, h1, l1;
      psplit2(p0, p1, h0, l0);
      psplit2(p2, p3, h1, l1);
      union { uint2 u; v4s v; } uh, ul;
      uh.u = make_uint2(h0, h1);
      ul.u = make_uint2(l0, l1);
      pH[qt] = uh.v;
      pL[qt] = ul.v;
    }

    bool resc = (al[0] != 1.f) | (al[1] != 1.f) | (al[2] != 1.f) | (al[3] != 1.f);
    if (__any(resc)) {
      #pragma unroll
      for (int mt = 0; mt < 3; mt++)
        #pragma unroll
        for (int qt = 0; qt < 4; qt++)
          ot[mt][qt] *= al[qt];
    }

    // O^T += V^T · P^T
    #pragma unroll
    for (int mt = 0; mt < 3; mt++) {
      #pragma unroll
      for (int qt = 0; qt < 4; qt++) {
        v4f acc = ot[mt][qt];
        acc = MFMA16(cvh[mt], pH[qt], acc);
        acc = MFMA16(cvl[mt], pH[qt], acc);
        acc = MFMA16(cvh[mt], pL[qt], acc);
        ot[mt][qt] = acc;
      }
    }
  }

  // ---- merge the 4 per-wave partials (block-local), write unnormalized ----
  __shared__ float Obuf[4][64][49];
  __shared__ float Mbuf[4][4][16];
  __shared__ float Lbuf[4][4][16];

  #pragma unroll
  for (int mt = 0; mt < 3; mt++)
    #pragma unroll
    for (int qt = 0; qt < 4; qt++)
      #pragma unroll
      for (int r = 0; r < 4; r++)
        Obuf[w][16 * qt + li][16 * mt + 4 * quad + r] = ot[mt][qt][r];
  if (quad == 0) {
    #pragma unroll
    for (int qt = 0; qt < 4; qt++) {
      Mbuf[w][qt][li] = m2[qt];
      Lbuf[w][qt][li] = lsum[qt];
    }
  }
  __syncthreads();

  // wave w handles qrows [16w, 16w+16); lane: row=li, cols quad*12..+11
  float M = Mbuf[0][w][li];
  #pragma unroll
  for (int sw = 1; sw < 4; sw++) M = fmaxf(M, Mbuf[sw][w][li]);
  float sc[4];
  float lt = 0.f;
  #pragma unroll
  for (int sw = 0; sw < 4; sw++) {
    sc[sw] = EXP2F(Mbuf[sw][w][li] - M);
    lt += Lbuf[sw][w][li] * sc[sw];
  }
  int orow = 16 * w + li;
  float* Obase = (z == 0) ? Opart0 : Opart1;
  float* Op = Obase + ((size_t)(head * 64 + qy) * 64 + orow) * 48 + quad * 12;
  #pragma unroll
  for (int g = 0; g < 3; g++) {
    float a0 = 0.f, a1 = 0.f, a2 = 0.f, a3 = 0.f;
    #pragma unroll
    for (int sw = 0; sw < 4; sw++) {
      const float* ob = &Obuf[sw][orow][quad * 12 + g * 4];
      a0 += ob[0] * sc[sw];
      a1 += ob[1] * sc[sw];
      a2 += ob[2] * sc[sw];
      a3 += ob[3] * sc[sw];
    }
    *(float4*)(Op + g * 4) = make_float4(a0, a1, a2, a3);
  }
  if (quad == 0) {
    size_t midx = ((size_t)(z * 8 + head) * 64 + qy) * 64 + orow;
    mpart[midx] = M;
    lpart[midx] = lt;
  }
}

// ---- combine the 2 KV-half partials, normalize, split to hi/lo ----
__global__ __launch_bounds__(256) void attn_merge_kernel(
    const float* __restrict__ Opart0, const float* __restrict__ Opart1,
    const float* __restrict__ mpart, const float* __restrict__ lpart,
    ushort* __restrict__ aoH, ushort* __restrict__ aoL)
{
  const int h = blockIdx.x, qt = blockIdx.y;
  const int tid = threadIdx.x;
  const int row = tid >> 2;
  const int cg = (tid & 3) * 12;
  const size_t tile = (size_t)h * 64 + qt;
  const size_t m0i = tile * 64 + row;
  const size_t m1i = (size_t)512 * 64 + m0i;
  float m0 = mpart[m0i], m1 = mpart[m1i];
  float l0 = lpart[m0i], l1 = lpart[m1i];
  float M = fmaxf(m0, m1);
  float s0 = EXP2F(m0 - M), s1 = EXP2F(m1 - M);
  float inv = 1.f / (l0 * s0 + l1 * s1);
  s0 *= inv; s1 *= inv;
  const float* O0 = Opart0 + (tile * 64 + row) * 48 + cg;
  const float* O1 = Opart1 + (tile * 64 + row) * 48 + cg;
  size_t outp = (size_t)(qt * 64 + row) * DIM + h * DH + cg;
  #pragma unroll
  for (int g = 0; g < 3; g++) {
    float4 a = *(const float4*)(O0 + g * 4);
    float4 b = *(const float4*)(O1 + g * 4);
    float v0 = a.x * s0 + b.x * s1;
    float v1 = a.y * s0 + b.y * s1;
    float v2 = a.z * s0 + b.z * s1;
    float v3 = a.w * s0 + b.w * s1;
    ushort4 H, L;
    bsplit(v0, H.x, L.x); bsplit(v1, H.y, L.y);
    bsplit(v2, H.z, L.z); bsplit(v3, H.w, L.w);
    *(ushort4*)(aoH + outp + g * 4) = H;
    *(ushort4*)(aoL + outp + g * 4) = L;
  }
}

// ======================= final projection + sigmoid =======================

__global__ __launch_bounds__(256) void out_kernel(const float* __restrict__ h,
    const float* __restrict__ Wout, const float* __restrict__ bout,
    float* __restrict__ out)
{
  int gw = (blockIdx.x * 256 + threadIdx.x) >> 6;
  int lane = threadIdx.x & 63;
  if (gw >= N_NODES) return;
  float s = 0.f;
  #pragma unroll
  for (int c = 0; c < 6; c++)
    s += h[(size_t)gw * DIM + lane + c * 64] * Wout[lane + c * 64];
  #pragma unroll
  for (int off = 32; off >= 1; off >>= 1) s += __shfl_xor(s, off, 64);
  if (lane == 0) out[gw] = 1.f / (1.f + __expf(-(s + bout[0])));
}

// ======================= launch =======================

extern "C" void kernel_launch(void* const* d_in, const int* in_sizes, int n_in,
                              void* d_out, int out_size, void* d_ws, size_t ws_size,
                              hipStream_t stream)
{
  const float* node_emb = (const float*)d_in[0];
  const int*   edge_index = (const int*)d_in[1];
  const float* W_conv = (const float*)d_in[2];
  const float* b_conv = (const float*)d_in[3];
  const float* W_in   = (const float*)d_in[4];
  const float* b_in   = (const float*)d_in[5];
  const float* W_ao   = (const float*)d_in[6];
  const float* b_ao   = (const float*)d_in[7];
  const float* W_out  = (const float*)d_in[8];
  const float* b_out  = (const float*)d_in[9];
  float* out = (float*)d_out;

  const size_t ND = (size_t)N_NODES * DIM;       // 1572864
  const size_t WI = (size_t)QKVD * DIM;          // 442368
  const size_t WC = (size_t)DIM * DIM;           // 147456

  float* h      = (float*)d_ws;
  ushort* aggH  = (ushort*)(h + ND);
  ushort* aggL  = aggH + ND;
  ushort* qhi   = aggL + ND;
  ushort* qlo   = qhi + ND;
  ushort* khi   = qlo + ND;
  ushort* klo   = khi + ND;
  ushort* vthi  = klo + ND;
  ushort* vtlo  = vthi + ND;
  ushort* aoH   = vtlo + ND;
  ushort* aoL   = aoH + ND;
  ushort* wiH   = aoL + ND;
  ushort* wiL   = wiH + WI;
  ushort* waoH  = wiL + WI;
  ushort* waoL  = waoH + WC;
  ushort* wctH  = waoL + WC;
  ushort* wctL  = wctH + 3 * WC;
  ushort* wfH   = wctL + 3 * WC;
  ushort* wfL   = wfH + 3 * WI;
  float* wibc   = (float*)(wfL + 3 * WI);
  float* Opart1 = wibc + 3 * QKVD;               // 8*64*64*48 = 1572864 floats
  float* mpart  = Opart1 + ND;                   // 2*8*64*64 = 65536
  float* lpart  = mpart + 65536;
  int* counts   = (int*)(lpart + 65536);
  int* offsets  = counts + N_NODES;
  int* cursor   = offsets + N_NODES + 1;
  int* ssrc     = cursor + N_NODES;

  // z=0 partials alias the agg hi/lo region (dead during attention: written by
  // aggregate, consumed by qkv_gemm, both strictly before attn in the stream).
  float* Opart0 = (float*)aggH;                  // 2*3.1MB = 6.3MB = ND floats

  const int* dst = edge_index;
  const int* src = edge_index + N_EDGES;

  // CSR build
  zero_counts_kernel<<<(N_NODES + 255) / 256, 256, 0, stream>>>(counts, cursor);
  count_kernel<<<N_EDGES / 256, 256, 0, stream>>>(dst, counts);
  scan_kernel<<<1, 1024, 0, stream>>>(counts, offsets);
  scatter_kernel<<<N_EDGES / 256, 256, 0, stream>>>(dst, src, offsets, cursor, ssrc);
  (void)hipMemcpyAsync(h, node_emb, ND * sizeof(float), hipMemcpyDeviceToDevice, stream);

  // weight prep
  transpose_split_kernel<<<dim3(12, 12, 3), dim3(32, 32), 0, stream>>>(W_conv, wctH, wctL);
  split_kernel<<<(int)(WI / 1024), 256, 0, stream>>>(W_in, wiH, wiL, (int)WI);
  split_kernel<<<(int)(WC / 1024), 256, 0, stream>>>(W_ao, waoH, waoL, (int)WC);
  wibc_kernel<<<864, 256, 0, stream>>>(W_in, b_conv, wibc);
  wprep_gemm<<<dim3(9, 3, 3), 256, 0, stream>>>(wiH, wiL, wctH, wctL, wfH, wfL);

  for (int l = 0; l < N_LAYERS; l++) {
    aggregate_kernel<<<N_NODES, 128, 0, stream>>>(h, ssrc, offsets, aggH, aggL);
    qkv_gemm<<<dim3(9, 32), 256, 0, stream>>>(
        wfH + (size_t)l * WI, wfL + (size_t)l * WI, aggH, aggL,
        wibc + (size_t)l * QKVD, b_in, counts,
        qhi, qlo, khi, klo, vthi, vtlo);
    attn_kernel<<<dim3(8, 64, 2), 256, 0, stream>>>(
        qhi, qlo, khi, klo, vthi, vtlo, Opart0, Opart1, mpart, lpart);
    attn_merge_kernel<<<dim3(8, 64), 256, 0, stream>>>(
        Opart0, Opart1, mpart, lpart, aoH, aoL);
    outproj_gemm<<<dim3(32, 3), 256, 0, stream>>>(
        aoH, aoL, waoH, waoL, b_ao, h);
  }
  out_kernel<<<1024, 256, 0, stream>>>(h, W_out, b_out, out);
}

// Round 6
// 811.404 us; speedup vs baseline: 1.4907x; 1.4907x over previous
//
#include <hip/hip_runtime.h>
#include <math.h>

#define N_NODES 4096
#define DIM 384
#define QKVD 1152
#define N_EDGES 131072
#define N_HEADS 8
#define DH 48
#define N_LAYERS 3

typedef short v4s __attribute__((ext_vector_type(4)));
typedef short v8s __attribute__((ext_vector_type(8)));
typedef float v4f __attribute__((ext_vector_type(4)));

#define MFMA32(A, B, C) __builtin_amdgcn_mfma_f32_16x16x32_bf16(A, B, C, 0, 0, 0)
#define MFMA16(A, B, C) __builtin_amdgcn_mfma_f32_16x16x16bf16_1k(A, B, C, 0, 0, 0)
#define EXP2F(x) __builtin_exp2f(x)

// ======================= CSR build (counting sort by dst) =======================

__global__ void zero_counts_kernel(int* counts, int* cursor) {
  int i = blockIdx.x * blockDim.x + threadIdx.x;
  if (i < N_NODES) { counts[i] = 0; cursor[i] = 0; }
}

__global__ void count_kernel(const int* __restrict__ dst, int* counts) {
  int e = blockIdx.x * blockDim.x + threadIdx.x;
  if (e < N_EDGES) atomicAdd(&counts[dst[e]], 1);
}

__global__ __launch_bounds__(1024) void scan_kernel(const int* __restrict__ counts,
                                                    int* __restrict__ offsets) {
  __shared__ int s[1024];
  int t = threadIdx.x;
  int base = t * 4;
  int c[4];
  int sum = 0;
  #pragma unroll
  for (int i = 0; i < 4; i++) { c[i] = counts[base + i]; sum += c[i]; }
  s[t] = sum;
  __syncthreads();
  for (int off = 1; off < 1024; off <<= 1) {
    int v = (t >= off) ? s[t - off] : 0;
    __syncthreads();
    s[t] += v;
    __syncthreads();
  }
  int excl = s[t] - sum;
  #pragma unroll
  for (int i = 0; i < 4; i++) { offsets[base + i] = excl; excl += c[i]; }
  if (t == 1023) offsets[N_NODES] = s[1023];
}

__global__ void scatter_kernel(const int* __restrict__ dst, const int* __restrict__ src,
                               const int* __restrict__ offsets, int* cursor,
                               int* __restrict__ ssrc) {
  int e = blockIdx.x * blockDim.x + threadIdx.x;
  if (e < N_EDGES) {
    int d = dst[e];
    int pos = atomicAdd(&cursor[d], 1);
    ssrc[offsets[d] + pos] = src[e];
  }
}

// ======================= bf16 split helpers =======================

__device__ __forceinline__ void bsplit(float v, ushort& hi, ushort& lo) {
  unsigned b = __float_as_uint(v);
  unsigned hb = b & 0xFFFF0000u;
  hi = (ushort)(b >> 16);
  float r = v - __uint_as_float(hb);
  lo = (ushort)(__float_as_uint(r) >> 16);
}

__device__ __forceinline__ void psplit2(float a, float b, unsigned& hi, unsigned& lo) {
  hi = __builtin_amdgcn_perm(__float_as_uint(b), __float_as_uint(a), 0x07060302u);
  float ra = a - __uint_as_float(hi << 16);
  float rb = b - __uint_as_float(hi & 0xFFFF0000u);
  lo = __builtin_amdgcn_perm(__float_as_uint(rb), __float_as_uint(ra), 0x07060302u);
}

// ======================= neighbor aggregation (+ split epilogue) =================

__global__ __launch_bounds__(128) void aggregate_kernel(const float* __restrict__ h,
    const int* __restrict__ ssrc, const int* __restrict__ offsets,
    ushort* __restrict__ aggH, ushort* __restrict__ aggL) {
  int i = blockIdx.x;
  int t = threadIdx.x;
  int e0 = offsets[i], e1 = offsets[i + 1];
  float a0 = 0.f, a1 = 0.f, a2 = 0.f;
  for (int e = e0; e < e1; e++) {
    const float* row = h + (size_t)ssrc[e] * DIM;
    a0 += row[t];
    a1 += row[t + 128];
    a2 += row[t + 256];
  }
  ushort h0, l0, h1, l1, h2, l2;
  bsplit(a0, h0, l0); bsplit(a1, h1, l1); bsplit(a2, h2, l2);
  size_t base = (size_t)i * DIM;
  aggH[base + t] = h0;       aggL[base + t] = l0;
  aggH[base + t + 128] = h1; aggL[base + t + 128] = l1;
  aggH[base + t + 256] = h2; aggL[base + t + 256] = l2;
}

// ======================= weight prep kernels =======================

__global__ void transpose_split_kernel(const float* __restrict__ Wc,
    ushort* __restrict__ wctH, ushort* __restrict__ wctL) {
  __shared__ float s[32][33];
  const int l = blockIdx.z;
  const float* W = Wc + (size_t)l * DIM * DIM;
  int tx = threadIdx.x, ty = threadIdx.y;
  s[ty][tx] = W[(size_t)(blockIdx.y * 32 + ty) * DIM + blockIdx.x * 32 + tx];
  __syncthreads();
  float v = s[tx][ty];
  ushort hi, lo;
  bsplit(v, hi, lo);
  size_t off = (size_t)l * DIM * DIM + (size_t)(blockIdx.x * 32 + ty) * DIM + blockIdx.y * 32 + tx;
  wctH[off] = hi;
  wctL[off] = lo;
}

__global__ void split_kernel(const float* __restrict__ src,
    ushort* __restrict__ hi, ushort* __restrict__ lo, int n) {
  int i = (blockIdx.x * 256 + threadIdx.x) * 4;
  if (i >= n) return;
  float4 v = *(const float4*)(src + i);
  ushort4 H, L;
  bsplit(v.x, H.x, L.x); bsplit(v.y, H.y, L.y);
  bsplit(v.z, H.z, L.z); bsplit(v.w, H.w, L.w);
  *(ushort4*)(hi + i) = H;
  *(ushort4*)(lo + i) = L;
}

// wibc[l][i] = dot(Wi[i,:], b_conv[l,:])
__global__ __launch_bounds__(256) void wibc_kernel(const float* __restrict__ Wi,
    const float* __restrict__ bconv, float* __restrict__ wibc) {
  int gw = (blockIdx.x * 256 + threadIdx.x) >> 6;
  int lane = threadIdx.x & 63;
  if (gw >= 3 * QKVD) return;
  int l = gw / QKVD, i = gw - l * QKVD;
  const float* w = Wi + (size_t)i * DIM;
  const float* b = bconv + (size_t)l * DIM;
  float s = 0.f;
  #pragma unroll
  for (int c = 0; c < 6; c++) s += w[lane + c * 64] * b[lane + c * 64];
  #pragma unroll
  for (int off = 32; off >= 1; off >>= 1) s += __shfl_xor(s, off, 64);
  if (lane == 0) wibc[gw] = s;
}

// ======================= split-bf16 MFMA GEMM core ==============================

template<int K>
__device__ __forceinline__ void mfma_core(
    const ushort* __restrict__ Ah, const ushort* __restrict__ Al,
    const ushort* __restrict__ Bh, const ushort* __restrict__ Bl,
    int aRow0, int bRow0, int li, int quad, v4f acc[4][4])
{
  for (int k0 = 0; k0 < K; k0 += 32) {
    v8s Afh[4], Afl[4], Bfh[4], Bfl[4];
    #pragma unroll
    for (int t = 0; t < 4; t++) {
      size_t ao = (size_t)(aRow0 + t * 16 + li) * K + k0 + quad * 8;
      size_t bo = (size_t)(bRow0 + t * 16 + li) * K + k0 + quad * 8;
      Afh[t] = *(const v8s*)(Ah + ao);
      Afl[t] = *(const v8s*)(Al + ao);
      Bfh[t] = *(const v8s*)(Bh + bo);
      Bfl[t] = *(const v8s*)(Bl + bo);
    }
    #pragma unroll
    for (int mt = 0; mt < 4; mt++)
      #pragma unroll
      for (int nt = 0; nt < 4; nt++) {
        v4f a = acc[mt][nt];
        a = MFMA32(Afh[mt], Bfh[nt], a);
        a = MFMA32(Afl[mt], Bfh[nt], a);
        a = MFMA32(Afh[mt], Bfl[nt], a);
        acc[mt][nt] = a;
      }
  }
}

// --- weight-prep GEMM: Wf[l] = Wi @ Wct[l] ---
__global__ __launch_bounds__(256) void wprep_gemm(
    const ushort* __restrict__ wiH, const ushort* __restrict__ wiL,
    const ushort* __restrict__ wctH, const ushort* __restrict__ wctL,
    ushort* __restrict__ wfH, ushort* __restrict__ wfL)
{
  const int l = blockIdx.z;
  const ushort* Bh = wctH + (size_t)l * DIM * DIM;
  const ushort* Bl = wctL + (size_t)l * DIM * DIM;
  ushort* oH = wfH + (size_t)l * QKVD * DIM;
  ushort* oL = wfL + (size_t)l * QKVD * DIM;
  const int tid = threadIdx.x;
  const int lane = tid & 63, li = lane & 15, quad = lane >> 4;
  const int w = tid >> 6, wm = w & 1, wn = w >> 1;
  const int aRow0 = blockIdx.x * 128 + wm * 64;
  const int bRow0 = blockIdx.y * 128 + wn * 64;
  v4f acc[4][4] = {};
  mfma_core<DIM>(wiH, wiL, Bh, Bl, aRow0, bRow0, li, quad, acc);
  #pragma unroll
  for (int mt = 0; mt < 4; mt++) {
    int i0 = aRow0 + mt * 16 + quad * 4;
    #pragma unroll
    for (int nt = 0; nt < 4; nt++) {
      int j = bRow0 + nt * 16 + li;
      #pragma unroll
      for (int r = 0; r < 4; r++) {
        ushort hi, lo;
        bsplit(acc[mt][nt][r], hi, lo);
        oH[(size_t)(i0 + r) * DIM + j] = hi;
        oL[(size_t)(i0 + r) * DIM + j] = lo;
      }
    }
  }
}

// --- fused qkv GEMM ---
__global__ __launch_bounds__(256) void qkv_gemm(
    const ushort* __restrict__ wfH, const ushort* __restrict__ wfL,
    const ushort* __restrict__ aggH, const ushort* __restrict__ aggL,
    const float* __restrict__ wibc_l, const float* __restrict__ b_in,
    const int* __restrict__ deg,
    ushort* __restrict__ qhi, ushort* __restrict__ qlo,
    ushort* __restrict__ khi, ushort* __restrict__ klo,
    ushort* __restrict__ vthi, ushort* __restrict__ vtlo)
{
  const int tid = threadIdx.x;
  const int lane = tid & 63, li = lane & 15, quad = lane >> 4;
  const int w = tid >> 6, wm = w & 1, wn = w >> 1;
  const int aRow0 = blockIdx.x * 128 + wm * 64;   // channel base
  const int bRow0 = blockIdx.y * 128 + wn * 64;   // node base
  v4f acc[4][4] = {};
  mfma_core<DIM>(wfH, wfL, aggH, aggL, aRow0, bRow0, li, quad, acc);

  const float cq = 0.20823507f;  // log2(e)/sqrt(48)
  int node[4]; float degf[4];
  #pragma unroll
  for (int nt = 0; nt < 4; nt++) {
    node[nt] = bRow0 + nt * 16 + li;
    degf[nt] = (float)deg[node[nt]];
  }
  #pragma unroll
  for (int mt = 0; mt < 4; mt++) {
    const int c0 = aRow0 + mt * 16 + quad * 4;
    const int part = c0 / DIM;
    const int cm = c0 - part * DIM;
    const int hd = cm / DH;
    const int d0 = cm - hd * DH;
    float wb[4], bb[4];
    #pragma unroll
    for (int r = 0; r < 4; r++) { wb[r] = wibc_l[c0 + r]; bb[r] = b_in[c0 + r]; }
    #pragma unroll
    for (int nt = 0; nt < 4; nt++) {
      float v0 = acc[mt][nt][0] + degf[nt] * wb[0] + bb[0];
      float v1 = acc[mt][nt][1] + degf[nt] * wb[1] + bb[1];
      float v2 = acc[mt][nt][2] + degf[nt] * wb[2] + bb[2];
      float v3 = acc[mt][nt][3] + degf[nt] * wb[3] + bb[3];
      if (part == 0) {
        v0 *= cq; v1 *= cq; v2 *= cq; v3 *= cq;
        ushort4 H, L;
        bsplit(v0, H.x, L.x); bsplit(v1, H.y, L.y);
        bsplit(v2, H.z, L.z); bsplit(v3, H.w, L.w);
        size_t off = ((size_t)hd * N_NODES + node[nt]) * DH + d0;
        *(ushort4*)(qhi + off) = H;
        *(ushort4*)(qlo + off) = L;
      } else if (part == 1) {
        ushort4 H, L;
        bsplit(v0, H.x, L.x); bsplit(v1, H.y, L.y);
        bsplit(v2, H.z, L.z); bsplit(v3, H.w, L.w);
        size_t off = ((size_t)hd * N_NODES + node[nt]) * DH + d0;
        *(ushort4*)(khi + off) = H;
        *(ushort4*)(klo + off) = L;
      } else {
        float vv[4] = {v0, v1, v2, v3};
        #pragma unroll
        for (int r = 0; r < 4; r++) {
          ushort hi, lo;
          bsplit(vv[r], hi, lo);
          size_t off = ((size_t)hd * DH + d0 + r) * N_NODES + node[nt];
          vthi[off] = hi;
          vtlo[off] = lo;
        }
      }
    }
  }
}

// --- attn-out GEMM: h = relu(ao @ Wao^T + b_ao + h) ---
__global__ __launch_bounds__(256) void outproj_gemm(
    const ushort* __restrict__ aoH, const ushort* __restrict__ aoL,
    const ushort* __restrict__ waoH, const ushort* __restrict__ waoL,
    const float* __restrict__ b_ao, float* __restrict__ h)
{
  const int tid = threadIdx.x;
  const int lane = tid & 63, li = lane & 15, quad = lane >> 4;
  const int w = tid >> 6, wm = w & 1, wn = w >> 1;
  const int aRow0 = blockIdx.x * 128 + wm * 64;   // node base
  const int bRow0 = blockIdx.y * 128 + wn * 64;   // channel base
  v4f acc[4][4] = {};
  mfma_core<DIM>(aoH, aoL, waoH, waoL, aRow0, bRow0, li, quad, acc);
  #pragma unroll
  for (int mt = 0; mt < 4; mt++) {
    int m0 = aRow0 + mt * 16 + quad * 4;
    #pragma unroll
    for (int nt = 0; nt < 4; nt++) {
      int n = bRow0 + nt * 16 + li;
      float ba = b_ao[n];
      #pragma unroll
      for (int r = 0; r < 4; r++) {
        size_t off = (size_t)(m0 + r) * DIM + n;
        float v = acc[mt][nt][r] + ba + h[off];
        h[off] = fmaxf(v, 0.f);
      }
    }
  }
}

// ======================= MFMA flash attention (split-bf16, KV-split 2) ==========
// grid (H=8, N/64=64, 2 KV-halves), 256 thr = 4 waves. Wave w owns kcol slice
// [kb+16w, kb+16w+16). 64 Q-rows per block. bounds(256,2): NOT 3 — R5 showed
// bounds-3 forces VGPR spills (~148 regs live). 2x unrolled ping-pong K-loop,
// unconditional prefetch (64-row overrun lands in adjacent mapped ws buffers,
// values never consumed), per-lane deferred lsum (no shfl in loop for l).

__global__ __launch_bounds__(256, 2) void attn_kernel(
    const ushort* __restrict__ qhi, const ushort* __restrict__ qlo,
    const ushort* __restrict__ khi, const ushort* __restrict__ klo,
    const ushort* __restrict__ vthi, const ushort* __restrict__ vtlo,
    float* __restrict__ Opart0, float* __restrict__ Opart1,
    float* __restrict__ mpart, float* __restrict__ lpart)
{
  const int head = blockIdx.x;
  const int qy = blockIdx.y;
  const int z = blockIdx.z;
  const int qBase = qy * 64;
  const int kb0 = z * (N_NODES / 2);
  const int tid = threadIdx.x;
  const int w = tid >> 6;
  const int lane = tid & 63;
  const int li = lane & 15, quad = lane >> 4;

  const size_t headQK = (size_t)head * N_NODES * DH;
  const size_t headV  = (size_t)head * DH * N_NODES;

  // resident Q fragments (4 q-tiles of 16 rows)
  v8s q0h[4], q0l[4];
  v4s q1h[4], q1l[4];
  #pragma unroll
  for (int qt = 0; qt < 4; qt++) {
    const ushort* qr = qhi + headQK + (size_t)(qBase + 16 * qt + li) * DH;
    const ushort* ql = qlo + headQK + (size_t)(qBase + 16 * qt + li) * DH;
    q0h[qt] = *(const v8s*)(qr + quad * 8);
    q0l[qt] = *(const v8s*)(ql + quad * 8);
    q1h[qt] = *(const v4s*)(qr + 32 + quad * 4);
    q1l[qt] = *(const v4s*)(ql + 32 + quad * 4);
  }

  v4f ot[3][4];
  #pragma unroll
  for (int mt = 0; mt < 3; mt++)
    #pragma unroll
    for (int qt = 0; qt < 4; qt++)
      ot[mt][qt] = (v4f){0.f, 0.f, 0.f, 0.f};
  float m2[4] = {-3.0e38f, -3.0e38f, -3.0e38f, -3.0e38f};
  float lsum[4] = {0.f, 0.f, 0.f, 0.f};

  const ushort* kh0 = khi + headQK + (size_t)(kb0 + 16 * w + li) * DH;
  const ushort* kl0 = klo + headQK + (size_t)(kb0 + 16 * w + li) * DH;
  const ushort* vh0 = vthi + headV + (size_t)li * N_NODES + kb0 + 16 * w + quad * 4;
  const ushort* vl0 = vtlo + headV + (size_t)li * N_NODES + kb0 + 16 * w + quad * 4;

  struct KV { v8s k0h, k0l; v4s k1h, k1l; v4s vh[3], vl[3]; };
  KV A, B;

  auto load_tile = [&](int t, KV& T) {
    const ushort* kh = kh0 + (size_t)t * (64 * DH);
    const ushort* kl = kl0 + (size_t)t * (64 * DH);
    T.k0h = *(const v8s*)(kh + quad * 8);
    T.k0l = *(const v8s*)(kl + quad * 8);
    T.k1h = *(const v4s*)(kh + 32 + quad * 4);
    T.k1l = *(const v4s*)(kl + 32 + quad * 4);
    const ushort* vh = vh0 + t * 64;
    const ushort* vl = vl0 + t * 64;
    #pragma unroll
    for (int mt = 0; mt < 3; mt++) {
      T.vh[mt] = *(const v4s*)(vh + (size_t)mt * (16 * N_NODES));
      T.vl[mt] = *(const v4s*)(vl + (size_t)mt * (16 * N_NODES));
    }
  };

  auto proc_tile = [&](const KV& T) {
    // S^T = K·Q^T (log2-domain scores via pre-scaled q)
    v4f s[4];
    #pragma unroll
    for (int qt = 0; qt < 4; qt++) {
      v4f acc = (v4f){0.f, 0.f, 0.f, 0.f};
      acc = MFMA32(T.k0h, q0h[qt], acc);
      acc = MFMA32(T.k0l, q0h[qt], acc);
      acc = MFMA32(T.k0h, q0l[qt], acc);
      acc = MFMA16(T.k1h, q1h[qt], acc);
      acc = MFMA16(T.k1l, q1h[qt], acc);
      acc = MFMA16(T.k1h, q1l[qt], acc);
      s[qt] = acc;
    }

    // online softmax (deferred per-lane lsum; cross-quad reduce only for max)
    v4s pH[4], pL[4];
    float al[4];
    #pragma unroll
    for (int qt = 0; qt < 4; qt++) {
      float mx = fmaxf(fmaxf(s[qt][0], s[qt][1]), fmaxf(s[qt][2], s[qt][3]));
      mx = fmaxf(mx, __shfl_xor(mx, 16, 64));
      mx = fmaxf(mx, __shfl_xor(mx, 32, 64));
      float mn = fmaxf(m2[qt], mx);
      float a = EXP2F(m2[qt] - mn);
      m2[qt] = mn;
      al[qt] = a;
      float p0 = EXP2F(s[qt][0] - mn);
      float p1 = EXP2F(s[qt][1] - mn);
      float p2 = EXP2F(s[qt][2] - mn);
      float p3 = EXP2F(s[qt][3] - mn);
      lsum[qt] = lsum[qt] * a + ((p0 + p1) + (p2 + p3));
      unsigned h0, l0, h1, l1;
      psplit2(p0, p1, h0, l0);
      psplit2(p2, p3, h1, l1);
      union { uint2 u; v4s v; } uh, ul;
      uh.u = make_uint2(h0, h1);
      ul.u = make_uint2(l0, l1);
      pH[qt] = uh.v;
      pL[qt] = ul.v;
    }

    bool resc = (al[0] != 1.f) | (al[1] != 1.f) | (al[2] != 1.f) | (al[3] != 1.f);
    if (__any(resc)) {
      #pragma unroll
      for (int mt = 0; mt < 3; mt++)
        #pragma unroll
        for (int qt = 0; qt < 4; qt++)
          ot[mt][qt] *= al[qt];
    }

    // O^T += V^T · P^T
    #pragma unroll
    for (int mt = 0; mt < 3; mt++) {
      #pragma unroll
      for (int qt = 0; qt < 4; qt++) {
        v4f acc = ot[mt][qt];
        acc = MFMA16(T.vh[mt], pH[qt], acc);
        acc = MFMA16(T.vl[mt], pH[qt], acc);
        acc = MFMA16(T.vh[mt], pL[qt], acc);
        ot[mt][qt] = acc;
      }
    }
  };

  load_tile(0, A);
  for (int it = 0; it < 32; it += 2) {
    load_tile(it + 1, B);
    proc_tile(A);
    load_tile(it + 2, A);   // it=30 prefetches tile 32: 64-row overrun into
                            // adjacent mapped ws buffer, values never consumed
    proc_tile(B);
  }

  // finish deferred lsum: reduce across quads (same m per row -> consistent)
  #pragma unroll
  for (int qt = 0; qt < 4; qt++) {
    lsum[qt] += __shfl_xor(lsum[qt], 16, 64);
    lsum[qt] += __shfl_xor(lsum[qt], 32, 64);
  }

  // ---- merge the 4 per-wave partials (block-local), write unnormalized ----
  __shared__ float Obuf[4][64][49];
  __shared__ float Mbuf[4][4][16];
  __shared__ float Lbuf[4][4][16];

  #pragma unroll
  for (int mt = 0; mt < 3; mt++)
    #pragma unroll
    for (int qt = 0; qt < 4; qt++)
      #pragma unroll
      for (int r = 0; r < 4; r++)
        Obuf[w][16 * qt + li][16 * mt + 4 * quad + r] = ot[mt][qt][r];
  if (quad == 0) {
    #pragma unroll
    for (int qt = 0; qt < 4; qt++) {
      Mbuf[w][qt][li] = m2[qt];
      Lbuf[w][qt][li] = lsum[qt];
    }
  }
  __syncthreads();

  // wave w handles qrows [16w, 16w+16); lane: row=li, cols quad*12..+11
  float M = Mbuf[0][w][li];
  #pragma unroll
  for (int sw = 1; sw < 4; sw++) M = fmaxf(M, Mbuf[sw][w][li]);
  float sc[4];
  float lt = 0.f;
  #pragma unroll
  for (int sw = 0; sw < 4; sw++) {
    sc[sw] = EXP2F(Mbuf[sw][w][li] - M);
    lt += Lbuf[sw][w][li] * sc[sw];
  }
  int orow = 16 * w + li;
  float* Obase = (z == 0) ? Opart0 : Opart1;
  float* Op = Obase + ((size_t)(head * 64 + qy) * 64 + orow) * 48 + quad * 12;
  #pragma unroll
  for (int g = 0; g < 3; g++) {
    float a0 = 0.f, a1 = 0.f, a2 = 0.f, a3 = 0.f;
    #pragma unroll
    for (int sw = 0; sw < 4; sw++) {
      const float* ob = &Obuf[sw][orow][quad * 12 + g * 4];
      a0 += ob[0] * sc[sw];
      a1 += ob[1] * sc[sw];
      a2 += ob[2] * sc[sw];
      a3 += ob[3] * sc[sw];
    }
    *(float4*)(Op + g * 4) = make_float4(a0, a1, a2, a3);
  }
  if (quad == 0) {
    size_t midx = ((size_t)(z * 8 + head) * 64 + qy) * 64 + orow;
    mpart[midx] = M;
    lpart[midx] = lt;
  }
}

// ---- combine the 2 KV-half partials, normalize, split to hi/lo ----
__global__ __launch_bounds__(256) void attn_merge_kernel(
    const float* __restrict__ Opart0, const float* __restrict__ Opart1,
    const float* __restrict__ mpart, const float* __restrict__ lpart,
    ushort* __restrict__ aoH, ushort* __restrict__ aoL)
{
  const int h = blockIdx.x, qt = blockIdx.y;
  const int tid = threadIdx.x;
  const int row = tid >> 2;
  const int cg = (tid & 3) * 12;
  const size_t tile = (size_t)h * 64 + qt;
  const size_t m0i = tile * 64 + row;
  const size_t m1i = (size_t)512 * 64 + m0i;
  float m0 = mpart[m0i], m1 = mpart[m1i];
  float l0 = lpart[m0i], l1 = lpart[m1i];
  float M = fmaxf(m0, m1);
  float s0 = EXP2F(m0 - M), s1 = EXP2F(m1 - M);
  float inv = 1.f / (l0 * s0 + l1 * s1);
  s0 *= inv; s1 *= inv;
  const float* O0 = Opart0 + (tile * 64 + row) * 48 + cg;
  const float* O1 = Opart1 + (tile * 64 + row) * 48 + cg;
  size_t outp = (size_t)(qt * 64 + row) * DIM + h * DH + cg;
  #pragma unroll
  for (int g = 0; g < 3; g++) {
    float4 a = *(const float4*)(O0 + g * 4);
    float4 b = *(const float4*)(O1 + g * 4);
    float v0 = a.x * s0 + b.x * s1;
    float v1 = a.y * s0 + b.y * s1;
    float v2 = a.z * s0 + b.z * s1;
    float v3 = a.w * s0 + b.w * s1;
    ushort4 H, L;
    bsplit(v0, H.x, L.x); bsplit(v1, H.y, L.y);
    bsplit(v2, H.z, L.z); bsplit(v3, H.w, L.w);
    *(ushort4*)(aoH + outp + g * 4) = H;
    *(ushort4*)(aoL + outp + g * 4) = L;
  }
}

// ======================= final projection + sigmoid =======================

__global__ __launch_bounds__(256) void out_kernel(const float* __restrict__ h,
    const float* __restrict__ Wout, const float* __restrict__ bout,
    float* __restrict__ out)
{
  int gw = (blockIdx.x * 256 + threadIdx.x) >> 6;
  int lane = threadIdx.x & 63;
  if (gw >= N_NODES) return;
  float s = 0.f;
  #pragma unroll
  for (int c = 0; c < 6; c++)
    s += h[(size_t)gw * DIM + lane + c * 64] * Wout[lane + c * 64];
  #pragma unroll
  for (int off = 32; off >= 1; off >>= 1) s += __shfl_xor(s, off, 64);
  if (lane == 0) out[gw] = 1.f / (1.f + __expf(-(s + bout[0])));
}

// ======================= launch =======================

extern "C" void kernel_launch(void* const* d_in, const int* in_sizes, int n_in,
                              void* d_out, int out_size, void* d_ws, size_t ws_size,
                              hipStream_t stream)
{
  const float* node_emb = (const float*)d_in[0];
  const int*   edge_index = (const int*)d_in[1];
  const float* W_conv = (const float*)d_in[2];
  const float* b_conv = (const float*)d_in[3];
  const float* W_in   = (const float*)d_in[4];
  const float* b_in   = (const float*)d_in[5];
  const float* W_ao   = (const float*)d_in[6];
  const float* b_ao   = (const float*)d_in[7];
  const float* W_out  = (const float*)d_in[8];
  const float* b_out  = (const float*)d_in[9];
  float* out = (float*)d_out;

  const size_t ND = (size_t)N_NODES * DIM;       // 1572864
  const size_t WI = (size_t)QKVD * DIM;          // 442368
  const size_t WC = (size_t)DIM * DIM;           // 147456

  float* h      = (float*)d_ws;
  ushort* aggH  = (ushort*)(h + ND);
  ushort* aggL  = aggH + ND;
  ushort* qhi   = aggL + ND;
  ushort* qlo   = qhi + ND;
  ushort* khi   = qlo + ND;
  ushort* klo   = khi + ND;
  ushort* vthi  = klo + ND;
  ushort* vtlo  = vthi + ND;
  ushort* aoH   = vtlo + ND;
  ushort* aoL   = aoH + ND;
  ushort* wiH   = aoL + ND;
  ushort* wiL   = wiH + WI;
  ushort* waoH  = wiL + WI;
  ushort* waoL  = waoH + WC;
  ushort* wctH  = waoL + WC;
  ushort* wctL  = wctH + 3 * WC;
  ushort* wfH   = wctL + 3 * WC;
  ushort* wfL   = wfH + 3 * WI;
  float* wibc   = (float*)(wfL + 3 * WI);
  float* Opart1 = wibc + 3 * QKVD;               // 8*64*64*48 = 1572864 floats
  float* mpart  = Opart1 + ND;                   // 2*8*64*64 = 65536
  float* lpart  = mpart + 65536;
  int* counts   = (int*)(lpart + 65536);
  int* offsets  = counts + N_NODES;
  int* cursor   = offsets + N_NODES + 1;
  int* ssrc     = cursor + N_NODES;

  // z=0 partials alias the agg hi/lo region (dead during attention: written by
  // aggregate, consumed by qkv_gemm, both strictly before attn in the stream).
  float* Opart0 = (float*)aggH;                  // ND floats

  const int* dst = edge_index;
  const int* src = edge_index + N_EDGES;

  // CSR build
  zero_counts_kernel<<<(N_NODES + 255) / 256, 256, 0, stream>>>(counts, cursor);
  count_kernel<<<N_EDGES / 256, 256, 0, stream>>>(dst, counts);
  scan_kernel<<<1, 1024, 0, stream>>>(counts, offsets);
  scatter_kernel<<<N_EDGES / 256, 256, 0, stream>>>(dst, src, offsets, cursor, ssrc);
  (void)hipMemcpyAsync(h, node_emb, ND * sizeof(float), hipMemcpyDeviceToDevice, stream);

  // weight prep
  transpose_split_kernel<<<dim3(12, 12, 3), dim3(32, 32), 0, stream>>>(W_conv, wctH, wctL);
  split_kernel<<<(int)(WI / 1024), 256, 0, stream>>>(W_in, wiH, wiL, (int)WI);
  split_kernel<<<(int)(WC / 1024), 256, 0, stream>>>(W_ao, waoH, waoL, (int)WC);
  wibc_kernel<<<864, 256, 0, stream>>>(W_in, b_conv, wibc);
  wprep_gemm<<<dim3(9, 3, 3), 256, 0, stream>>>(wiH, wiL, wctH, wctL, wfH, wfL);

  for (int l = 0; l < N_LAYERS; l++) {
    aggregate_kernel<<<N_NODES, 128, 0, stream>>>(h, ssrc, offsets, aggH, aggL);
    qkv_gemm<<<dim3(9, 32), 256, 0, stream>>>(
        wfH + (size_t)l * WI, wfL + (size_t)l * WI, aggH, aggL,
        wibc + (size_t)l * QKVD, b_in, counts,
        qhi, qlo, khi, klo, vthi, vtlo);
    attn_kernel<<<dim3(8, 64, 2), 256, 0, stream>>>(
        qhi, qlo, khi, klo, vthi, vtlo, Opart0, Opart1, mpart, lpart);
    attn_merge_kernel<<<dim3(8, 64), 256, 0, stream>>>(
        Opart0, Opart1, mpart, lpart, aoH, aoL);
    outproj_gemm<<<dim3(32, 3), 256, 0, stream>>>(
        aoH, aoL, waoH, waoL, b_ao, h);
  }
  out_kernel<<<1024, 256, 0, stream>>>(h, W_out, b_out, out);
}

// Round 8
// 804.726 us; speedup vs baseline: 1.5031x; 1.0083x over previous
//
#include <hip/hip_runtime.h>
#include <math.h>

#define N_NODES 4096
#define DIM 384
#define QKVD 1152
#define N_EDGES 131072
#define N_HEADS 8
#define DH 48
#define N_LAYERS 3

typedef short v4s __attribute__((ext_vector_type(4)));
typedef short v8s __attribute__((ext_vector_type(8)));
typedef float v4f __attribute__((ext_vector_type(4)));

#define MFMA32(A, B, C) __builtin_amdgcn_mfma_f32_16x16x32_bf16(A, B, C, 0, 0, 0)
#define MFMA16(A, B, C) __builtin_amdgcn_mfma_f32_16x16x16bf16_1k(A, B, C, 0, 0, 0)
#define EXP2F(x) __builtin_exp2f(x)

// ======================= CSR build (counting sort by dst) =======================

__global__ void zero_counts_kernel(int* counts, int* cursor) {
  int i = blockIdx.x * blockDim.x + threadIdx.x;
  if (i < N_NODES) { counts[i] = 0; cursor[i] = 0; }
}

__global__ void count_kernel(const int* __restrict__ dst, int* counts) {
  int e = blockIdx.x * blockDim.x + threadIdx.x;
  if (e < N_EDGES) atomicAdd(&counts[dst[e]], 1);
}

__global__ __launch_bounds__(1024) void scan_kernel(const int* __restrict__ counts,
                                                    int* __restrict__ offsets) {
  __shared__ int s[1024];
  int t = threadIdx.x;
  int base = t * 4;
  int c[4];
  int sum = 0;
  #pragma unroll
  for (int i = 0; i < 4; i++) { c[i] = counts[base + i]; sum += c[i]; }
  s[t] = sum;
  __syncthreads();
  for (int off = 1; off < 1024; off <<= 1) {
    int v = (t >= off) ? s[t - off] : 0;
    __syncthreads();
    s[t] += v;
    __syncthreads();
  }
  int excl = s[t] - sum;
  #pragma unroll
  for (int i = 0; i < 4; i++) { offsets[base + i] = excl; excl += c[i]; }
  if (t == 1023) offsets[N_NODES] = s[1023];
}

__global__ void scatter_kernel(const int* __restrict__ dst, const int* __restrict__ src,
                               const int* __restrict__ offsets, int* cursor,
                               int* __restrict__ ssrc) {
  int e = blockIdx.x * blockDim.x + threadIdx.x;
  if (e < N_EDGES) {
    int d = dst[e];
    int pos = atomicAdd(&cursor[d], 1);
    ssrc[offsets[d] + pos] = src[e];
  }
}

// ======================= bf16 split helpers =======================

__device__ __forceinline__ void bsplit(float v, ushort& hi, ushort& lo) {
  unsigned b = __float_as_uint(v);
  unsigned hb = b & 0xFFFF0000u;
  hi = (ushort)(b >> 16);
  float r = v - __uint_as_float(hb);
  lo = (ushort)(__float_as_uint(r) >> 16);
}

__device__ __forceinline__ void psplit2(float a, float b, unsigned& hi, unsigned& lo) {
  hi = __builtin_amdgcn_perm(__float_as_uint(b), __float_as_uint(a), 0x07060302u);
  float ra = a - __uint_as_float(hi << 16);
  float rb = b - __uint_as_float(hi & 0xFFFF0000u);
  lo = __builtin_amdgcn_perm(__float_as_uint(rb), __float_as_uint(ra), 0x07060302u);
}

// ======================= neighbor aggregation (+ split epilogue) =================

__global__ __launch_bounds__(128) void aggregate_kernel(const float* __restrict__ h,
    const int* __restrict__ ssrc, const int* __restrict__ offsets,
    ushort* __restrict__ aggH, ushort* __restrict__ aggL) {
  int i = blockIdx.x;
  int t = threadIdx.x;
  int e0 = offsets[i], e1 = offsets[i + 1];
  float a0 = 0.f, a1 = 0.f, a2 = 0.f;
  int e = e0;
  for (; e + 2 <= e1; e += 2) {       // 2x unroll: 6 independent loads in flight
    const float* r0 = h + (size_t)ssrc[e] * DIM;
    const float* r1 = h + (size_t)ssrc[e + 1] * DIM;
    float x0 = r0[t], x1 = r0[t + 128], x2 = r0[t + 256];
    float y0 = r1[t], y1 = r1[t + 128], y2 = r1[t + 256];
    a0 += x0; a1 += x1; a2 += x2;
    a0 += y0; a1 += y1; a2 += y2;
  }
  if (e < e1) {
    const float* row = h + (size_t)ssrc[e] * DIM;
    a0 += row[t]; a1 += row[t + 128]; a2 += row[t + 256];
  }
  ushort h0, l0, h1, l1, h2, l2;
  bsplit(a0, h0, l0); bsplit(a1, h1, l1); bsplit(a2, h2, l2);
  size_t base = (size_t)i * DIM;
  aggH[base + t] = h0;       aggL[base + t] = l0;
  aggH[base + t + 128] = h1; aggL[base + t + 128] = l1;
  aggH[base + t + 256] = h2; aggL[base + t + 256] = l2;
}

// ======================= weight prep kernels =======================

__global__ void transpose_split_kernel(const float* __restrict__ Wc,
    ushort* __restrict__ wctH, ushort* __restrict__ wctL) {
  __shared__ float s[32][33];
  const int l = blockIdx.z;
  const float* W = Wc + (size_t)l * DIM * DIM;
  int tx = threadIdx.x, ty = threadIdx.y;
  s[ty][tx] = W[(size_t)(blockIdx.y * 32 + ty) * DIM + blockIdx.x * 32 + tx];
  __syncthreads();
  float v = s[tx][ty];
  ushort hi, lo;
  bsplit(v, hi, lo);
  size_t off = (size_t)l * DIM * DIM + (size_t)(blockIdx.x * 32 + ty) * DIM + blockIdx.y * 32 + tx;
  wctH[off] = hi;
  wctL[off] = lo;
}

__global__ void split_kernel(const float* __restrict__ src,
    ushort* __restrict__ hi, ushort* __restrict__ lo, int n) {
  int i = (blockIdx.x * 256 + threadIdx.x) * 4;
  if (i >= n) return;
  float4 v = *(const float4*)(src + i);
  ushort4 H, L;
  bsplit(v.x, H.x, L.x); bsplit(v.y, H.y, L.y);
  bsplit(v.z, H.z, L.z); bsplit(v.w, H.w, L.w);
  *(ushort4*)(hi + i) = H;
  *(ushort4*)(lo + i) = L;
}

// wibc[l][i] = dot(Wi[i,:], b_conv[l,:])
__global__ __launch_bounds__(256) void wibc_kernel(const float* __restrict__ Wi,
    const float* __restrict__ bconv, float* __restrict__ wibc) {
  int gw = (blockIdx.x * 256 + threadIdx.x) >> 6;
  int lane = threadIdx.x & 63;
  if (gw >= 3 * QKVD) return;
  int l = gw / QKVD, i = gw - l * QKVD;
  const float* w = Wi + (size_t)i * DIM;
  const float* b = bconv + (size_t)l * DIM;
  float s = 0.f;
  #pragma unroll
  for (int c = 0; c < 6; c++) s += w[lane + c * 64] * b[lane + c * 64];
  #pragma unroll
  for (int off = 32; off >= 1; off >>= 1) s += __shfl_xor(s, off, 64);
  if (lane == 0) wibc[gw] = s;
}

// ======================= split-bf16 MFMA GEMM core ==============================

template<int K>
__device__ __forceinline__ void mfma_core(
    const ushort* __restrict__ Ah, const ushort* __restrict__ Al,
    const ushort* __restrict__ Bh, const ushort* __restrict__ Bl,
    int aRow0, int bRow0, int li, int quad, v4f acc[4][4])
{
  for (int k0 = 0; k0 < K; k0 += 32) {
    v8s Afh[4], Afl[4], Bfh[4], Bfl[4];
    #pragma unroll
    for (int t = 0; t < 4; t++) {
      size_t ao = (size_t)(aRow0 + t * 16 + li) * K + k0 + quad * 8;
      size_t bo = (size_t)(bRow0 + t * 16 + li) * K + k0 + quad * 8;
      Afh[t] = *(const v8s*)(Ah + ao);
      Afl[t] = *(const v8s*)(Al + ao);
      Bfh[t] = *(const v8s*)(Bh + bo);
      Bfl[t] = *(const v8s*)(Bl + bo);
    }
    #pragma unroll
    for (int mt = 0; mt < 4; mt++)
      #pragma unroll
      for (int nt = 0; nt < 4; nt++) {
        v4f a = acc[mt][nt];
        a = MFMA32(Afh[mt], Bfh[nt], a);
        a = MFMA32(Afl[mt], Bfh[nt], a);
        a = MFMA32(Afh[mt], Bfl[nt], a);
        acc[mt][nt] = a;
      }
  }
}

// --- weight-prep GEMM: Wf[l] = Wi @ Wct[l] ---
__global__ __launch_bounds__(256) void wprep_gemm(
    const ushort* __restrict__ wiH, const ushort* __restrict__ wiL,
    const ushort* __restrict__ wctH, const ushort* __restrict__ wctL,
    ushort* __restrict__ wfH, ushort* __restrict__ wfL)
{
  const int l = blockIdx.z;
  const ushort* Bh = wctH + (size_t)l * DIM * DIM;
  const ushort* Bl = wctL + (size_t)l * DIM * DIM;
  ushort* oH = wfH + (size_t)l * QKVD * DIM;
  ushort* oL = wfL + (size_t)l * QKVD * DIM;
  const int tid = threadIdx.x;
  const int lane = tid & 63, li = lane & 15, quad = lane >> 4;
  const int w = tid >> 6, wm = w & 1, wn = w >> 1;
  const int aRow0 = blockIdx.x * 128 + wm * 64;
  const int bRow0 = blockIdx.y * 128 + wn * 64;
  v4f acc[4][4] = {};
  mfma_core<DIM>(wiH, wiL, Bh, Bl, aRow0, bRow0, li, quad, acc);
  #pragma unroll
  for (int mt = 0; mt < 4; mt++) {
    int i0 = aRow0 + mt * 16 + quad * 4;
    #pragma unroll
    for (int nt = 0; nt < 4; nt++) {
      int j = bRow0 + nt * 16 + li;
      #pragma unroll
      for (int r = 0; r < 4; r++) {
        ushort hi, lo;
        bsplit(acc[mt][nt][r], hi, lo);
        oH[(size_t)(i0 + r) * DIM + j] = hi;
        oL[(size_t)(i0 + r) * DIM + j] = lo;
      }
    }
  }
}

// --- fused qkv GEMM ---
__global__ __launch_bounds__(256) void qkv_gemm(
    const ushort* __restrict__ wfH, const ushort* __restrict__ wfL,
    const ushort* __restrict__ aggH, const ushort* __restrict__ aggL,
    const float* __restrict__ wibc_l, const float* __restrict__ b_in,
    const int* __restrict__ deg,
    ushort* __restrict__ qhi, ushort* __restrict__ qlo,
    ushort* __restrict__ khi, ushort* __restrict__ klo,
    ushort* __restrict__ vthi, ushort* __restrict__ vtlo)
{
  const int tid = threadIdx.x;
  const int lane = tid & 63, li = lane & 15, quad = lane >> 4;
  const int w = tid >> 6, wm = w & 1, wn = w >> 1;
  const int aRow0 = blockIdx.x * 128 + wm * 64;   // channel base
  const int bRow0 = blockIdx.y * 128 + wn * 64;   // node base
  v4f acc[4][4] = {};
  mfma_core<DIM>(wfH, wfL, aggH, aggL, aRow0, bRow0, li, quad, acc);

  const float cq = 0.20823507f;  // log2(e)/sqrt(48)
  int node[4]; float degf[4];
  #pragma unroll
  for (int nt = 0; nt < 4; nt++) {
    node[nt] = bRow0 + nt * 16 + li;
    degf[nt] = (float)deg[node[nt]];
  }
  #pragma unroll
  for (int mt = 0; mt < 4; mt++) {
    const int c0 = aRow0 + mt * 16 + quad * 4;
    const int part = c0 / DIM;
    const int cm = c0 - part * DIM;
    const int hd = cm / DH;
    const int d0 = cm - hd * DH;
    float wb[4], bb[4];
    #pragma unroll
    for (int r = 0; r < 4; r++) { wb[r] = wibc_l[c0 + r]; bb[r] = b_in[c0 + r]; }
    #pragma unroll
    for (int nt = 0; nt < 4; nt++) {
      float v0 = acc[mt][nt][0] + degf[nt] * wb[0] + bb[0];
      float v1 = acc[mt][nt][1] + degf[nt] * wb[1] + bb[1];
      float v2 = acc[mt][nt][2] + degf[nt] * wb[2] + bb[2];
      float v3 = acc[mt][nt][3] + degf[nt] * wb[3] + bb[3];
      if (part == 0) {
        v0 *= cq; v1 *= cq; v2 *= cq; v3 *= cq;
        ushort4 H, L;
        bsplit(v0, H.x, L.x); bsplit(v1, H.y, L.y);
        bsplit(v2, H.z, L.z); bsplit(v3, H.w, L.w);
        size_t off = ((size_t)hd * N_NODES + node[nt]) * DH + d0;
        *(ushort4*)(qhi + off) = H;
        *(ushort4*)(qlo + off) = L;
      } else if (part == 1) {
        ushort4 H, L;
        bsplit(v0, H.x, L.x); bsplit(v1, H.y, L.y);
        bsplit(v2, H.z, L.z); bsplit(v3, H.w, L.w);
        size_t off = ((size_t)hd * N_NODES + node[nt]) * DH + d0;
        *(ushort4*)(khi + off) = H;
        *(ushort4*)(klo + off) = L;
      } else {
        float vv[4] = {v0, v1, v2, v3};
        #pragma unroll
        for (int r = 0; r < 4; r++) {
          ushort hi, lo;
          bsplit(vv[r], hi, lo);
          size_t off = ((size_t)hd * DH + d0 + r) * N_NODES + node[nt];
          vthi[off] = hi;
          vtlo[off] = lo;
        }
      }
    }
  }
}

// --- attn-out GEMM: h = relu(ao @ Wao^T + b_ao + h) ---
__global__ __launch_bounds__(256) void outproj_gemm(
    const ushort* __restrict__ aoH, const ushort* __restrict__ aoL,
    const ushort* __restrict__ waoH, const ushort* __restrict__ waoL,
    const float* __restrict__ b_ao, float* __restrict__ h)
{
  const int tid = threadIdx.x;
  const int lane = tid & 63, li = lane & 15, quad = lane >> 4;
  const int w = tid >> 6, wm = w & 1, wn = w >> 1;
  const int aRow0 = blockIdx.x * 128 + wm * 64;   // node base
  const int bRow0 = blockIdx.y * 128 + wn * 64;   // channel base
  v4f acc[4][4] = {};
  mfma_core<DIM>(aoH, aoL, waoH, waoL, aRow0, bRow0, li, quad, acc);
  #pragma unroll
  for (int mt = 0; mt < 4; mt++) {
    int m0 = aRow0 + mt * 16 + quad * 4;
    #pragma unroll
    for (int nt = 0; nt < 4; nt++) {
      int n = bRow0 + nt * 16 + li;
      float ba = b_ao[n];
      #pragma unroll
      for (int r = 0; r < 4; r++) {
        size_t off = (size_t)(m0 + r) * DIM + n;
        float v = acc[mt][nt][r] + ba + h[off];
        h[off] = fmaxf(v, 0.f);
      }
    }
  }
}

// ======================= MFMA flash attention (split-bf16, KV-split 2) ==========
// grid (H=8, N/64=64, 2 KV-halves), 256 thr = 4 waves. Wave w owns kcol slice
// [kb+16w, kb+16w+16). 64 Q-rows per block, bounds(256,2) (3 blocks/CU is
// impossible: HW VGPR steps at 128 — R5 post-mortem). GUARDED rescale: keep a
// running base m2 but move it only when the tile max exceeds m2+40 (rare).
// Quiescent tiles skip alpha-exp2 + the 48 rescale mults + lsum*a — exact
// softmax after final 1/l normalization; exp2 arg bounded <= 40 so p <= 2^40,
// l <= 2^49, O << fp32 max (R7's UNguarded fixed-m overflowed: no layernorm in
// this net, score spreads are huge). m2 init -3e38 -> tile 0 takes the guard
// path with alpha = exp2(-inf) = 0, self-initializing.

__global__ __launch_bounds__(256, 2) void attn_kernel(
    const ushort* __restrict__ qhi, const ushort* __restrict__ qlo,
    const ushort* __restrict__ khi, const ushort* __restrict__ klo,
    const ushort* __restrict__ vthi, const ushort* __restrict__ vtlo,
    float* __restrict__ Opart0, float* __restrict__ Opart1,
    float* __restrict__ mpart, float* __restrict__ lpart)
{
  const int head = blockIdx.x;
  const int qy = blockIdx.y;
  const int z = blockIdx.z;
  const int qBase = qy * 64;
  const int kb0 = z * (N_NODES / 2);
  const int tid = threadIdx.x;
  const int w = tid >> 6;
  const int lane = tid & 63;
  const int li = lane & 15, quad = lane >> 4;

  const size_t headQK = (size_t)head * N_NODES * DH;
  const size_t headV  = (size_t)head * DH * N_NODES;

  // resident Q fragments (4 q-tiles of 16 rows)
  v8s q0h[4], q0l[4];
  v4s q1h[4], q1l[4];
  #pragma unroll
  for (int qt = 0; qt < 4; qt++) {
    const ushort* qr = qhi + headQK + (size_t)(qBase + 16 * qt + li) * DH;
    const ushort* ql = qlo + headQK + (size_t)(qBase + 16 * qt + li) * DH;
    q0h[qt] = *(const v8s*)(qr + quad * 8);
    q0l[qt] = *(const v8s*)(ql + quad * 8);
    q1h[qt] = *(const v4s*)(qr + 32 + quad * 4);
    q1l[qt] = *(const v4s*)(ql + 32 + quad * 4);
  }

  v4f ot[3][4];
  #pragma unroll
  for (int mt = 0; mt < 3; mt++)
    #pragma unroll
    for (int qt = 0; qt < 4; qt++)
      ot[mt][qt] = (v4f){0.f, 0.f, 0.f, 0.f};
  float m2[4] = {-3.0e38f, -3.0e38f, -3.0e38f, -3.0e38f};
  float lsum[4] = {0.f, 0.f, 0.f, 0.f};

  const ushort* kh0 = khi + headQK + (size_t)(kb0 + 16 * w + li) * DH;
  const ushort* kl0 = klo + headQK + (size_t)(kb0 + 16 * w + li) * DH;
  const ushort* vh0 = vthi + headV + (size_t)li * N_NODES + kb0 + 16 * w + quad * 4;
  const ushort* vl0 = vtlo + headV + (size_t)li * N_NODES + kb0 + 16 * w + quad * 4;

  struct KV { v8s k0h, k0l; v4s k1h, k1l; v4s vh[3], vl[3]; };
  KV A, B;

  auto load_tile = [&](int t, KV& T) {
    const ushort* kh = kh0 + (size_t)t * (64 * DH);
    const ushort* kl = kl0 + (size_t)t * (64 * DH);
    T.k0h = *(const v8s*)(kh + quad * 8);
    T.k0l = *(const v8s*)(kl + quad * 8);
    T.k1h = *(const v4s*)(kh + 32 + quad * 4);
    T.k1l = *(const v4s*)(kl + 32 + quad * 4);
    const ushort* vh = vh0 + t * 64;
    const ushort* vl = vl0 + t * 64;
    #pragma unroll
    for (int mt = 0; mt < 3; mt++) {
      T.vh[mt] = *(const v4s*)(vh + (size_t)mt * (16 * N_NODES));
      T.vl[mt] = *(const v4s*)(vl + (size_t)mt * (16 * N_NODES));
    }
  };

  auto proc_tile = [&](const KV& T) {
    // S^T = K·Q^T (log2-domain scores via pre-scaled q)
    v4f s[4];
    #pragma unroll
    for (int qt = 0; qt < 4; qt++) {
      v4f acc = (v4f){0.f, 0.f, 0.f, 0.f};
      acc = MFMA32(T.k0h, q0h[qt], acc);
      acc = MFMA32(T.k0l, q0h[qt], acc);
      acc = MFMA32(T.k0h, q0l[qt], acc);
      acc = MFMA16(T.k1h, q1h[qt], acc);
      acc = MFMA16(T.k1l, q1h[qt], acc);
      acc = MFMA16(T.k1h, q1l[qt], acc);
      s[qt] = acc;
    }

    // guarded-base softmax: rescale only when tile max exceeds m2+40
    v4s pH[4], pL[4];
    #pragma unroll
    for (int qt = 0; qt < 4; qt++) {
      float mx = fmaxf(fmaxf(s[qt][0], s[qt][1]), fmaxf(s[qt][2], s[qt][3]));
      mx = fmaxf(mx, __shfl_xor(mx, 16, 64));
      mx = fmaxf(mx, __shfl_xor(mx, 32, 64));   // row-uniform across quads
      if (__any(mx > m2[qt] + 40.f)) {          // rare path
        float mn = fmaxf(m2[qt], mx);
        float a = EXP2F(m2[qt] - mn);           // 0 on first tile
        m2[qt] = mn;
        lsum[qt] *= a;
        #pragma unroll
        for (int mt = 0; mt < 3; mt++) ot[mt][qt] *= a;
      }
      float p0 = EXP2F(s[qt][0] - m2[qt]);      // bounded <= 2^40
      float p1 = EXP2F(s[qt][1] - m2[qt]);
      float p2 = EXP2F(s[qt][2] - m2[qt]);
      float p3 = EXP2F(s[qt][3] - m2[qt]);
      lsum[qt] += (p0 + p1) + (p2 + p3);
      unsigned h0, l0, h1, l1;
      psplit2(p0, p1, h0, l0);
      psplit2(p2, p3, h1, l1);
      union { uint2 u; v4s v; } uh, ul;
      uh.u = make_uint2(h0, h1);
      ul.u = make_uint2(l0, l1);
      pH[qt] = uh.v;
      pL[qt] = ul.v;
    }

    // O^T += V^T · P^T
    #pragma unroll
    for (int mt = 0; mt < 3; mt++) {
      #pragma unroll
      for (int qt = 0; qt < 4; qt++) {
        v4f acc = ot[mt][qt];
        acc = MFMA16(T.vh[mt], pH[qt], acc);
        acc = MFMA16(T.vl[mt], pH[qt], acc);
        acc = MFMA16(T.vh[mt], pL[qt], acc);
        ot[mt][qt] = acc;
      }
    }
  };

  load_tile(0, A);
  for (int it = 0; it < 32; it += 2) {
    load_tile(it + 1, B);
    proc_tile(A);
    load_tile(it + 2, A);   // it=30 prefetches tile 32: overrun lands in
                            // adjacent mapped ws buffers, values never consumed
    proc_tile(B);
  }

  // finish deferred lsum: reduce across quads (m2 row-uniform -> consistent)
  #pragma unroll
  for (int qt = 0; qt < 4; qt++) {
    lsum[qt] += __shfl_xor(lsum[qt], 16, 64);
    lsum[qt] += __shfl_xor(lsum[qt], 32, 64);
  }

  // ---- merge the 4 per-wave partials (block-local), write unnormalized ----
  __shared__ float Obuf[4][64][49];
  __shared__ float Mbuf[4][4][16];
  __shared__ float Lbuf[4][4][16];

  #pragma unroll
  for (int mt = 0; mt < 3; mt++)
    #pragma unroll
    for (int qt = 0; qt < 4; qt++)
      #pragma unroll
      for (int r = 0; r < 4; r++)
        Obuf[w][16 * qt + li][16 * mt + 4 * quad + r] = ot[mt][qt][r];
  if (quad == 0) {
    #pragma unroll
    for (int qt = 0; qt < 4; qt++) {
      Mbuf[w][qt][li] = m2[qt];
      Lbuf[w][qt][li] = lsum[qt];
    }
  }
  __syncthreads();

  // wave w handles qrows [16w, 16w+16); lane: row=li, cols quad*12..+11
  float M = Mbuf[0][w][li];
  #pragma unroll
  for (int sw = 1; sw < 4; sw++) M = fmaxf(M, Mbuf[sw][w][li]);
  float sc[4];
  float lt = 0.f;
  #pragma unroll
  for (int sw = 0; sw < 4; sw++) {
    sc[sw] = EXP2F(Mbuf[sw][w][li] - M);
    lt += Lbuf[sw][w][li] * sc[sw];
  }
  int orow = 16 * w + li;
  float* Obase = (z == 0) ? Opart0 : Opart1;
  float* Op = Obase + ((size_t)(head * 64 + qy) * 64 + orow) * 48 + quad * 12;
  #pragma unroll
  for (int g = 0; g < 3; g++) {
    float a0 = 0.f, a1 = 0.f, a2 = 0.f, a3 = 0.f;
    #pragma unroll
    for (int sw = 0; sw < 4; sw++) {
      const float* ob = &Obuf[sw][orow][quad * 12 + g * 4];
      a0 += ob[0] * sc[sw];
      a1 += ob[1] * sc[sw];
      a2 += ob[2] * sc[sw];
      a3 += ob[3] * sc[sw];
    }
    *(float4*)(Op + g * 4) = make_float4(a0, a1, a2, a3);
  }
  if (quad == 0) {
    size_t midx = ((size_t)(z * 8 + head) * 64 + qy) * 64 + orow;
    mpart[midx] = M;
    lpart[midx] = lt;
  }
}

// ---- combine the 2 KV-half partials, normalize, split to hi/lo ----
__global__ __launch_bounds__(256) void attn_merge_kernel(
    const float* __restrict__ Opart0, const float* __restrict__ Opart1,
    const float* __restrict__ mpart, const float* __restrict__ lpart,
    ushort* __restrict__ aoH, ushort* __restrict__ aoL)
{
  const int h = blockIdx.x, qt = blockIdx.y;
  const int tid = threadIdx.x;
  const int row = tid >> 2;
  const int cg = (tid & 3) * 12;
  const size_t tile = (size_t)h * 64 + qt;
  const size_t m0i = tile * 64 + row;
  const size_t m1i = (size_t)512 * 64 + m0i;
  float m0 = mpart[m0i], m1 = mpart[m1i];
  float l0 = lpart[m0i], l1 = lpart[m1i];
  float M = fmaxf(m0, m1);
  float s0 = EXP2F(m0 - M), s1 = EXP2F(m1 - M);
  float inv = 1.f / (l0 * s0 + l1 * s1);
  s0 *= inv; s1 *= inv;
  const float* O0 = Opart0 + (tile * 64 + row) * 48 + cg;
  const float* O1 = Opart1 + (tile * 64 + row) * 48 + cg;
  size_t outp = (size_t)(qt * 64 + row) * DIM + h * DH + cg;
  #pragma unroll
  for (int g = 0; g < 3; g++) {
    float4 a = *(const float4*)(O0 + g * 4);
    float4 b = *(const float4*)(O1 + g * 4);
    float v0 = a.x * s0 + b.x * s1;
    float v1 = a.y * s0 + b.y * s1;
    float v2 = a.z * s0 + b.z * s1;
    float v3 = a.w * s0 + b.w * s1;
    ushort4 H, L;
    bsplit(v0, H.x, L.x); bsplit(v1, H.y, L.y);
    bsplit(v2, H.z, L.z); bsplit(v3, H.w, L.w);
    *(ushort4*)(aoH + outp + g * 4) = H;
    *(ushort4*)(aoL + outp + g * 4) = L;
  }
}

// ======================= final projection + sigmoid =======================

__global__ __launch_bounds__(256) void out_kernel(const float* __restrict__ h,
    const float* __restrict__ Wout, const float* __restrict__ bout,
    float* __restrict__ out)
{
  int gw = (blockIdx.x * 256 + threadIdx.x) >> 6;
  int lane = threadIdx.x & 63;
  if (gw >= N_NODES) return;
  float s = 0.f;
  #pragma unroll
  for (int c = 0; c < 6; c++)
    s += h[(size_t)gw * DIM + lane + c * 64] * Wout[lane + c * 64];
  #pragma unroll
  for (int off = 32; off >= 1; off >>= 1) s += __shfl_xor(s, off, 64);
  if (lane == 0) out[gw] = 1.f / (1.f + __expf(-(s + bout[0])));
}

// ======================= launch =======================

extern "C" void kernel_launch(void* const* d_in, const int* in_sizes, int n_in,
                              void* d_out, int out_size, void* d_ws, size_t ws_size,
                              hipStream_t stream)
{
  const float* node_emb = (const float*)d_in[0];
  const int*   edge_index = (const int*)d_in[1];
  const float* W_conv = (const float*)d_in[2];
  const float* b_conv = (const float*)d_in[3];
  const float* W_in   = (const float*)d_in[4];
  const float* b_in   = (const float*)d_in[5];
  const float* W_ao   = (const float*)d_in[6];
  const float* b_ao   = (const float*)d_in[7];
  const float* W_out  = (const float*)d_in[8];
  const float* b_out  = (const float*)d_in[9];
  float* out = (float*)d_out;

  const size_t ND = (size_t)N_NODES * DIM;       // 1572864
  const size_t WI = (size_t)QKVD * DIM;          // 442368
  const size_t WC = (size_t)DIM * DIM;           // 147456

  float* h      = (float*)d_ws;
  ushort* aggH  = (ushort*)(h + ND);
  ushort* aggL  = aggH + ND;
  ushort* qhi   = aggL + ND;
  ushort* qlo   = qhi + ND;
  ushort* khi   = qlo + ND;
  ushort* klo   = khi + ND;
  ushort* vthi  = klo + ND;
  ushort* vtlo  = vthi + ND;
  ushort* aoH   = vtlo + ND;
  ushort* aoL   = aoH + ND;
  ushort* wiH   = aoL + ND;
  ushort* wiL   = wiH + WI;
  ushort* waoH  = wiL + WI;
  ushort* waoL  = waoH + WC;
  ushort* wctH  = waoL + WC;
  ushort* wctL  = wctH + 3 * WC;
  ushort* wfH   = wctL + 3 * WC;
  ushort* wfL   = wfH + 3 * WI;
  float* wibc   = (float*)(wfL + 3 * WI);
  float* Opart1 = wibc + 3 * QKVD;               // 8*64*64*48 = 1572864 floats
  float* mpart  = Opart1 + ND;                   // 2*8*64*64 = 65536
  float* lpart  = mpart + 65536;
  int* counts   = (int*)(lpart + 65536);
  int* offsets  = counts + N_NODES;
  int* cursor   = offsets + N_NODES + 1;
  int* ssrc     = cursor + N_NODES;

  // z=0 partials alias the agg hi/lo region (dead during attention: written by
  // aggregate, consumed by qkv_gemm, both strictly before attn in the stream).
  float* Opart0 = (float*)aggH;                  // ND floats

  const int* dst = edge_index;
  const int* src = edge_index + N_EDGES;

  // CSR build
  zero_counts_kernel<<<(N_NODES + 255) / 256, 256, 0, stream>>>(counts, cursor);
  count_kernel<<<N_EDGES / 256, 256, 0, stream>>>(dst, counts);
  scan_kernel<<<1, 1024, 0, stream>>>(counts, offsets);
  scatter_kernel<<<N_EDGES / 256, 256, 0, stream>>>(dst, src, offsets, cursor, ssrc);
  (void)hipMemcpyAsync(h, node_emb, ND * sizeof(float), hipMemcpyDeviceToDevice, stream);

  // weight prep
  transpose_split_kernel<<<dim3(12, 12, 3), dim3(32, 32), 0, stream>>>(W_conv, wctH, wctL);
  split_kernel<<<(int)(WI / 1024), 256, 0, stream>>>(W_in, wiH, wiL, (int)WI);
  split_kernel<<<(int)(WC / 1024), 256, 0, stream>>>(W_ao, waoH, waoL, (int)WC);
  wibc_kernel<<<864, 256, 0, stream>>>(W_in, b_conv, wibc);
  wprep_gemm<<<dim3(9, 3, 3), 256, 0, stream>>>(wiH, wiL, wctH, wctL, wfH, wfL);

  for (int l = 0; l < N_LAYERS; l++) {
    aggregate_kernel<<<N_NODES, 128, 0, stream>>>(h, ssrc, offsets, aggH, aggL);
    qkv_gemm<<<dim3(9, 32), 256, 0, stream>>>(
        wfH + (size_t)l * WI, wfL + (size_t)l * WI, aggH, aggL,
        wibc + (size_t)l * QKVD, b_in, counts,
        qhi, qlo, khi, klo, vthi, vtlo);
    attn_kernel<<<dim3(8, 64, 2), 256, 0, stream>>>(
        qhi, qlo, khi, klo, vthi, vtlo, Opart0, Opart1, mpart, lpart);
    attn_merge_kernel<<<dim3(8, 64), 256, 0, stream>>>(
        Opart0, Opart1, mpart, lpart, aoH, aoL);
    outproj_gemm<<<dim3(32, 3), 256, 0, stream>>>(
        aoH, aoL, waoH, waoL, b_ao, h);
  }
  out_kernel<<<1024, 256, 0, stream>>>(h, W_out, b_out, out);
}

// Round 9
// 790.218 us; speedup vs baseline: 1.5307x; 1.0184x over previous
//
#include <hip/hip_runtime.h>
#include <math.h>

#define N_NODES 4096
#define DIM 384
#define QKVD 1152
#define N_EDGES 131072
#define N_HEADS 8
#define DH 48
#define N_LAYERS 3

typedef short v4s __attribute__((ext_vector_type(4)));
typedef short v8s __attribute__((ext_vector_type(8)));
typedef float v4f __attribute__((ext_vector_type(4)));

#define MFMA32(A, B, C) __builtin_amdgcn_mfma_f32_16x16x32_bf16(A, B, C, 0, 0, 0)
#define MFMA16(A, B, C) __builtin_amdgcn_mfma_f32_16x16x16bf16_1k(A, B, C, 0, 0, 0)
#define EXP2F(x) __builtin_exp2f(x)

// ======================= CSR build (counting sort by dst) =======================

__global__ void zero_counts_kernel(int* counts, int* cursor) {
  int i = blockIdx.x * blockDim.x + threadIdx.x;
  if (i < N_NODES) { counts[i] = 0; cursor[i] = 0; }
}

__global__ void count_kernel(const int* __restrict__ dst, int* counts) {
  int e = blockIdx.x * blockDim.x + threadIdx.x;
  if (e < N_EDGES) atomicAdd(&counts[dst[e]], 1);
}

__global__ __launch_bounds__(1024) void scan_kernel(const int* __restrict__ counts,
                                                    int* __restrict__ offsets) {
  __shared__ int s[1024];
  int t = threadIdx.x;
  int base = t * 4;
  int c[4];
  int sum = 0;
  #pragma unroll
  for (int i = 0; i < 4; i++) { c[i] = counts[base + i]; sum += c[i]; }
  s[t] = sum;
  __syncthreads();
  for (int off = 1; off < 1024; off <<= 1) {
    int v = (t >= off) ? s[t - off] : 0;
    __syncthreads();
    s[t] += v;
    __syncthreads();
  }
  int excl = s[t] - sum;
  #pragma unroll
  for (int i = 0; i < 4; i++) { offsets[base + i] = excl; excl += c[i]; }
  if (t == 1023) offsets[N_NODES] = s[1023];
}

__global__ void scatter_kernel(const int* __restrict__ dst, const int* __restrict__ src,
                               const int* __restrict__ offsets, int* cursor,
                               int* __restrict__ ssrc) {
  int e = blockIdx.x * blockDim.x + threadIdx.x;
  if (e < N_EDGES) {
    int d = dst[e];
    int pos = atomicAdd(&cursor[d], 1);
    ssrc[offsets[d] + pos] = src[e];
  }
}

// ======================= bf16 split helpers =======================

__device__ __forceinline__ void bsplit(float v, ushort& hi, ushort& lo) {
  unsigned b = __float_as_uint(v);
  unsigned hb = b & 0xFFFF0000u;
  hi = (ushort)(b >> 16);
  float r = v - __uint_as_float(hb);
  lo = (ushort)(__float_as_uint(r) >> 16);
}

__device__ __forceinline__ void psplit2(float a, float b, unsigned& hi, unsigned& lo) {
  hi = __builtin_amdgcn_perm(__float_as_uint(b), __float_as_uint(a), 0x07060302u);
  float ra = a - __uint_as_float(hi << 16);
  float rb = b - __uint_as_float(hi & 0xFFFF0000u);
  lo = __builtin_amdgcn_perm(__float_as_uint(rb), __float_as_uint(ra), 0x07060302u);
}

// ======================= neighbor aggregation (+ split epilogue) =================

__global__ __launch_bounds__(128) void aggregate_kernel(const float* __restrict__ h,
    const int* __restrict__ ssrc, const int* __restrict__ offsets,
    ushort* __restrict__ aggH, ushort* __restrict__ aggL) {
  int i = blockIdx.x;
  int t = threadIdx.x;
  int e0 = offsets[i], e1 = offsets[i + 1];
  float a0 = 0.f, a1 = 0.f, a2 = 0.f;
  int e = e0;
  for (; e + 2 <= e1; e += 2) {       // 2x unroll: 6 independent loads in flight
    const float* r0 = h + (size_t)ssrc[e] * DIM;
    const float* r1 = h + (size_t)ssrc[e + 1] * DIM;
    float x0 = r0[t], x1 = r0[t + 128], x2 = r0[t + 256];
    float y0 = r1[t], y1 = r1[t + 128], y2 = r1[t + 256];
    a0 += x0; a1 += x1; a2 += x2;
    a0 += y0; a1 += y1; a2 += y2;
  }
  if (e < e1) {
    const float* row = h + (size_t)ssrc[e] * DIM;
    a0 += row[t]; a1 += row[t + 128]; a2 += row[t + 256];
  }
  ushort h0, l0, h1, l1, h2, l2;
  bsplit(a0, h0, l0); bsplit(a1, h1, l1); bsplit(a2, h2, l2);
  size_t base = (size_t)i * DIM;
  aggH[base + t] = h0;       aggL[base + t] = l0;
  aggH[base + t + 128] = h1; aggL[base + t + 128] = l1;
  aggH[base + t + 256] = h2; aggL[base + t + 256] = l2;
}

// ======================= weight prep kernels =======================

__global__ void transpose_split_kernel(const float* __restrict__ Wc,
    ushort* __restrict__ wctH, ushort* __restrict__ wctL) {
  __shared__ float s[32][33];
  const int l = blockIdx.z;
  const float* W = Wc + (size_t)l * DIM * DIM;
  int tx = threadIdx.x, ty = threadIdx.y;
  s[ty][tx] = W[(size_t)(blockIdx.y * 32 + ty) * DIM + blockIdx.x * 32 + tx];
  __syncthreads();
  float v = s[tx][ty];
  ushort hi, lo;
  bsplit(v, hi, lo);
  size_t off = (size_t)l * DIM * DIM + (size_t)(blockIdx.x * 32 + ty) * DIM + blockIdx.y * 32 + tx;
  wctH[off] = hi;
  wctL[off] = lo;
}

__global__ void split_kernel(const float* __restrict__ src,
    ushort* __restrict__ hi, ushort* __restrict__ lo, int n) {
  int i = (blockIdx.x * 256 + threadIdx.x) * 4;
  if (i >= n) return;
  float4 v = *(const float4*)(src + i);
  ushort4 H, L;
  bsplit(v.x, H.x, L.x); bsplit(v.y, H.y, L.y);
  bsplit(v.z, H.z, L.z); bsplit(v.w, H.w, L.w);
  *(ushort4*)(hi + i) = H;
  *(ushort4*)(lo + i) = L;
}

// wibc[l][i] = dot(Wi[i,:], b_conv[l,:])
__global__ __launch_bounds__(256) void wibc_kernel(const float* __restrict__ Wi,
    const float* __restrict__ bconv, float* __restrict__ wibc) {
  int gw = (blockIdx.x * 256 + threadIdx.x) >> 6;
  int lane = threadIdx.x & 63;
  if (gw >= 3 * QKVD) return;
  int l = gw / QKVD, i = gw - l * QKVD;
  const float* w = Wi + (size_t)i * DIM;
  const float* b = bconv + (size_t)l * DIM;
  float s = 0.f;
  #pragma unroll
  for (int c = 0; c < 6; c++) s += w[lane + c * 64] * b[lane + c * 64];
  #pragma unroll
  for (int off = 32; off >= 1; off >>= 1) s += __shfl_xor(s, off, 64);
  if (lane == 0) wibc[gw] = s;
}

// ======================= split-bf16 MFMA GEMM core ==============================

template<int K>
__device__ __forceinline__ void mfma_core(
    const ushort* __restrict__ Ah, const ushort* __restrict__ Al,
    const ushort* __restrict__ Bh, const ushort* __restrict__ Bl,
    int aRow0, int bRow0, int li, int quad, v4f acc[4][4])
{
  for (int k0 = 0; k0 < K; k0 += 32) {
    v8s Afh[4], Afl[4], Bfh[4], Bfl[4];
    #pragma unroll
    for (int t = 0; t < 4; t++) {
      size_t ao = (size_t)(aRow0 + t * 16 + li) * K + k0 + quad * 8;
      size_t bo = (size_t)(bRow0 + t * 16 + li) * K + k0 + quad * 8;
      Afh[t] = *(const v8s*)(Ah + ao);
      Afl[t] = *(const v8s*)(Al + ao);
      Bfh[t] = *(const v8s*)(Bh + bo);
      Bfl[t] = *(const v8s*)(Bl + bo);
    }
    #pragma unroll
    for (int mt = 0; mt < 4; mt++)
      #pragma unroll
      for (int nt = 0; nt < 4; nt++) {
        v4f a = acc[mt][nt];
        a = MFMA32(Afh[mt], Bfh[nt], a);
        a = MFMA32(Afl[mt], Bfh[nt], a);
        a = MFMA32(Afh[mt], Bfl[nt], a);
        acc[mt][nt] = a;
      }
  }
}

// --- weight-prep GEMM: Wf[l] = Wi @ Wct[l] ---
__global__ __launch_bounds__(256) void wprep_gemm(
    const ushort* __restrict__ wiH, const ushort* __restrict__ wiL,
    const ushort* __restrict__ wctH, const ushort* __restrict__ wctL,
    ushort* __restrict__ wfH, ushort* __restrict__ wfL)
{
  const int l = blockIdx.z;
  const ushort* Bh = wctH + (size_t)l * DIM * DIM;
  const ushort* Bl = wctL + (size_t)l * DIM * DIM;
  ushort* oH = wfH + (size_t)l * QKVD * DIM;
  ushort* oL = wfL + (size_t)l * QKVD * DIM;
  const int tid = threadIdx.x;
  const int lane = tid & 63, li = lane & 15, quad = lane >> 4;
  const int w = tid >> 6, wm = w & 1, wn = w >> 1;
  const int aRow0 = blockIdx.x * 128 + wm * 64;
  const int bRow0 = blockIdx.y * 128 + wn * 64;
  v4f acc[4][4] = {};
  mfma_core<DIM>(wiH, wiL, Bh, Bl, aRow0, bRow0, li, quad, acc);
  #pragma unroll
  for (int mt = 0; mt < 4; mt++) {
    int i0 = aRow0 + mt * 16 + quad * 4;
    #pragma unroll
    for (int nt = 0; nt < 4; nt++) {
      int j = bRow0 + nt * 16 + li;
      #pragma unroll
      for (int r = 0; r < 4; r++) {
        ushort hi, lo;
        bsplit(acc[mt][nt][r], hi, lo);
        oH[(size_t)(i0 + r) * DIM + j] = hi;
        oL[(size_t)(i0 + r) * DIM + j] = lo;
      }
    }
  }
}

// --- fused qkv GEMM ---
__global__ __launch_bounds__(256) void qkv_gemm(
    const ushort* __restrict__ wfH, const ushort* __restrict__ wfL,
    const ushort* __restrict__ aggH, const ushort* __restrict__ aggL,
    const float* __restrict__ wibc_l, const float* __restrict__ b_in,
    const int* __restrict__ deg,
    ushort* __restrict__ qhi, ushort* __restrict__ qlo,
    ushort* __restrict__ khi, ushort* __restrict__ klo,
    ushort* __restrict__ vthi, ushort* __restrict__ vtlo)
{
  const int tid = threadIdx.x;
  const int lane = tid & 63, li = lane & 15, quad = lane >> 4;
  const int w = tid >> 6, wm = w & 1, wn = w >> 1;
  const int aRow0 = blockIdx.x * 128 + wm * 64;   // channel base
  const int bRow0 = blockIdx.y * 128 + wn * 64;   // node base
  v4f acc[4][4] = {};
  mfma_core<DIM>(wfH, wfL, aggH, aggL, aRow0, bRow0, li, quad, acc);

  const float cq = 0.20823507f;  // log2(e)/sqrt(48)
  int node[4]; float degf[4];
  #pragma unroll
  for (int nt = 0; nt < 4; nt++) {
    node[nt] = bRow0 + nt * 16 + li;
    degf[nt] = (float)deg[node[nt]];
  }
  #pragma unroll
  for (int mt = 0; mt < 4; mt++) {
    const int c0 = aRow0 + mt * 16 + quad * 4;
    const int part = c0 / DIM;
    const int cm = c0 - part * DIM;
    const int hd = cm / DH;
    const int d0 = cm - hd * DH;
    float wb[4], bb[4];
    #pragma unroll
    for (int r = 0; r < 4; r++) { wb[r] = wibc_l[c0 + r]; bb[r] = b_in[c0 + r]; }
    #pragma unroll
    for (int nt = 0; nt < 4; nt++) {
      float v0 = acc[mt][nt][0] + degf[nt] * wb[0] + bb[0];
      float v1 = acc[mt][nt][1] + degf[nt] * wb[1] + bb[1];
      float v2 = acc[mt][nt][2] + degf[nt] * wb[2] + bb[2];
      float v3 = acc[mt][nt][3] + degf[nt] * wb[3] + bb[3];
      if (part == 0) {
        v0 *= cq; v1 *= cq; v2 *= cq; v3 *= cq;
        ushort4 H, L;
        bsplit(v0, H.x, L.x); bsplit(v1, H.y, L.y);
        bsplit(v2, H.z, L.z); bsplit(v3, H.w, L.w);
        size_t off = ((size_t)hd * N_NODES + node[nt]) * DH + d0;
        *(ushort4*)(qhi + off) = H;
        *(ushort4*)(qlo + off) = L;
      } else if (part == 1) {
        ushort4 H, L;
        bsplit(v0, H.x, L.x); bsplit(v1, H.y, L.y);
        bsplit(v2, H.z, L.z); bsplit(v3, H.w, L.w);
        size_t off = ((size_t)hd * N_NODES + node[nt]) * DH + d0;
        *(ushort4*)(khi + off) = H;
        *(ushort4*)(klo + off) = L;
      } else {
        float vv[4] = {v0, v1, v2, v3};
        #pragma unroll
        for (int r = 0; r < 4; r++) {
          ushort hi, lo;
          bsplit(vv[r], hi, lo);
          size_t off = ((size_t)hd * DH + d0 + r) * N_NODES + node[nt];
          vthi[off] = hi;
          vtlo[off] = lo;
        }
      }
    }
  }
}

// --- attn-out GEMM: h = relu(ao @ Wao^T + b_ao + h) ---
__global__ __launch_bounds__(256) void outproj_gemm(
    const ushort* __restrict__ aoH, const ushort* __restrict__ aoL,
    const ushort* __restrict__ waoH, const ushort* __restrict__ waoL,
    const float* __restrict__ b_ao, float* __restrict__ h)
{
  const int tid = threadIdx.x;
  const int lane = tid & 63, li = lane & 15, quad = lane >> 4;
  const int w = tid >> 6, wm = w & 1, wn = w >> 1;
  const int aRow0 = blockIdx.x * 128 + wm * 64;   // node base
  const int bRow0 = blockIdx.y * 128 + wn * 64;   // channel base
  v4f acc[4][4] = {};
  mfma_core<DIM>(aoH, aoL, waoH, waoL, aRow0, bRow0, li, quad, acc);
  #pragma unroll
  for (int mt = 0; mt < 4; mt++) {
    int m0 = aRow0 + mt * 16 + quad * 4;
    #pragma unroll
    for (int nt = 0; nt < 4; nt++) {
      int n = bRow0 + nt * 16 + li;
      float ba = b_ao[n];
      #pragma unroll
      for (int r = 0; r < 4; r++) {
        size_t off = (size_t)(m0 + r) * DIM + n;
        float v = acc[mt][nt][r] + ba + h[off];
        h[off] = fmaxf(v, 0.f);
      }
    }
  }
}

// ======================= MFMA flash attention (split-bf16, KV-split 2) ==========
// grid (N/64=64, H=8, 2 KV-halves) — q-tile is blockIdx.x so CONSECUTIVE block
// ids share head+z: each XCD's resident blocks stream the SAME K/V sequence
// (R8 had head on x → 8 heads × 1.57 MB working set thrashed the 4 MB per-XCD
// L2; FETCH 9.3 MB > unique data). 256 thr = 4 waves; wave w owns kcols
// [kb+16w, +16). bounds(256,2) (VGPR steps at 128 — R5). Guarded rescale
// (R8, exact): base m2 moves only when per-lane tile max exceeds m2+40; the
// row-max shuffles live INSIDE the rare branch (identical m2 sequence).

__global__ __launch_bounds__(256, 2) void attn_kernel(
    const ushort* __restrict__ qhi, const ushort* __restrict__ qlo,
    const ushort* __restrict__ khi, const ushort* __restrict__ klo,
    const ushort* __restrict__ vthi, const ushort* __restrict__ vtlo,
    float* __restrict__ Opart0, float* __restrict__ Opart1,
    float* __restrict__ mpart, float* __restrict__ lpart)
{
  const int head = blockIdx.y;
  const int qy = blockIdx.x;
  const int z = blockIdx.z;
  const int qBase = qy * 64;
  const int kb0 = z * (N_NODES / 2);
  const int tid = threadIdx.x;
  const int w = tid >> 6;
  const int lane = tid & 63;
  const int li = lane & 15, quad = lane >> 4;

  const size_t headQK = (size_t)head * N_NODES * DH;
  const size_t headV  = (size_t)head * DH * N_NODES;

  // resident Q fragments (4 q-tiles of 16 rows)
  v8s q0h[4], q0l[4];
  v4s q1h[4], q1l[4];
  #pragma unroll
  for (int qt = 0; qt < 4; qt++) {
    const ushort* qr = qhi + headQK + (size_t)(qBase + 16 * qt + li) * DH;
    const ushort* ql = qlo + headQK + (size_t)(qBase + 16 * qt + li) * DH;
    q0h[qt] = *(const v8s*)(qr + quad * 8);
    q0l[qt] = *(const v8s*)(ql + quad * 8);
    q1h[qt] = *(const v4s*)(qr + 32 + quad * 4);
    q1l[qt] = *(const v4s*)(ql + 32 + quad * 4);
  }

  v4f ot[3][4];
  #pragma unroll
  for (int mt = 0; mt < 3; mt++)
    #pragma unroll
    for (int qt = 0; qt < 4; qt++)
      ot[mt][qt] = (v4f){0.f, 0.f, 0.f, 0.f};
  float m2[4] = {-3.0e38f, -3.0e38f, -3.0e38f, -3.0e38f};
  float lsum[4] = {0.f, 0.f, 0.f, 0.f};

  const ushort* kh0 = khi + headQK + (size_t)(kb0 + 16 * w + li) * DH;
  const ushort* kl0 = klo + headQK + (size_t)(kb0 + 16 * w + li) * DH;
  const ushort* vh0 = vthi + headV + (size_t)li * N_NODES + kb0 + 16 * w + quad * 4;
  const ushort* vl0 = vtlo + headV + (size_t)li * N_NODES + kb0 + 16 * w + quad * 4;

  struct KV { v8s k0h, k0l; v4s k1h, k1l; v4s vh[3], vl[3]; };
  KV A, B;

  auto load_tile = [&](int t, KV& T) {
    const ushort* kh = kh0 + (size_t)t * (64 * DH);
    const ushort* kl = kl0 + (size_t)t * (64 * DH);
    T.k0h = *(const v8s*)(kh + quad * 8);
    T.k0l = *(const v8s*)(kl + quad * 8);
    T.k1h = *(const v4s*)(kh + 32 + quad * 4);
    T.k1l = *(const v4s*)(kl + 32 + quad * 4);
    const ushort* vh = vh0 + t * 64;
    const ushort* vl = vl0 + t * 64;
    #pragma unroll
    for (int mt = 0; mt < 3; mt++) {
      T.vh[mt] = *(const v4s*)(vh + (size_t)mt * (16 * N_NODES));
      T.vl[mt] = *(const v4s*)(vl + (size_t)mt * (16 * N_NODES));
    }
  };

  auto proc_tile = [&](const KV& T) {
    // S^T = K·Q^T (log2-domain scores via pre-scaled q)
    v4f s[4];
    #pragma unroll
    for (int qt = 0; qt < 4; qt++) {
      v4f acc = (v4f){0.f, 0.f, 0.f, 0.f};
      acc = MFMA32(T.k0h, q0h[qt], acc);
      acc = MFMA32(T.k0l, q0h[qt], acc);
      acc = MFMA32(T.k0h, q0l[qt], acc);
      acc = MFMA16(T.k1h, q1h[qt], acc);
      acc = MFMA16(T.k1l, q1h[qt], acc);
      acc = MFMA16(T.k1h, q1l[qt], acc);
      s[qt] = acc;
    }

    // guarded-base softmax: rescale only when tile max exceeds m2+40 (rare).
    // __any over per-lane max == row-max test; shuffles only in rare path.
    v4s pH[4], pL[4];
    #pragma unroll
    for (int qt = 0; qt < 4; qt++) {
      float mx = fmaxf(fmaxf(s[qt][0], s[qt][1]), fmaxf(s[qt][2], s[qt][3]));
      if (__any(mx > m2[qt] + 40.f)) {          // wave-uniform branch
        float mr = fmaxf(mx, __shfl_xor(mx, 16, 64));
        mr = fmaxf(mr, __shfl_xor(mr, 32, 64)); // row-uniform new max
        float mn = fmaxf(m2[qt], mr);
        float a = EXP2F(m2[qt] - mn);           // 0 on first tile
        m2[qt] = mn;
        lsum[qt] *= a;
        #pragma unroll
        for (int mt = 0; mt < 3; mt++) ot[mt][qt] *= a;
      }
      float p0 = EXP2F(s[qt][0] - m2[qt]);      // bounded <= 2^40
      float p1 = EXP2F(s[qt][1] - m2[qt]);
      float p2 = EXP2F(s[qt][2] - m2[qt]);
      float p3 = EXP2F(s[qt][3] - m2[qt]);
      lsum[qt] += (p0 + p1) + (p2 + p3);
      unsigned h0, l0, h1, l1;
      psplit2(p0, p1, h0, l0);
      psplit2(p2, p3, h1, l1);
      union { uint2 u; v4s v; } uh, ul;
      uh.u = make_uint2(h0, h1);
      ul.u = make_uint2(l0, l1);
      pH[qt] = uh.v;
      pL[qt] = ul.v;
    }

    // O^T += V^T · P^T
    #pragma unroll
    for (int mt = 0; mt < 3; mt++) {
      #pragma unroll
      for (int qt = 0; qt < 4; qt++) {
        v4f acc = ot[mt][qt];
        acc = MFMA16(T.vh[mt], pH[qt], acc);
        acc = MFMA16(T.vl[mt], pH[qt], acc);
        acc = MFMA16(T.vh[mt], pL[qt], acc);
        ot[mt][qt] = acc;
      }
    }
  };

  load_tile(0, A);
  for (int it = 0; it < 32; it += 2) {
    load_tile(it + 1, B);
    proc_tile(A);
    load_tile(it + 2, A);   // it=30 prefetches tile 32: overrun lands in
                            // adjacent mapped ws buffers, values never consumed
    proc_tile(B);
  }

  // finish deferred lsum: reduce across quads (m2 row-uniform -> consistent)
  #pragma unroll
  for (int qt = 0; qt < 4; qt++) {
    lsum[qt] += __shfl_xor(lsum[qt], 16, 64);
    lsum[qt] += __shfl_xor(lsum[qt], 32, 64);
  }

  // ---- merge the 4 per-wave partials (block-local), write unnormalized ----
  __shared__ float Obuf[4][64][49];
  __shared__ float Mbuf[4][4][16];
  __shared__ float Lbuf[4][4][16];

  #pragma unroll
  for (int mt = 0; mt < 3; mt++)
    #pragma unroll
    for (int qt = 0; qt < 4; qt++)
      #pragma unroll
      for (int r = 0; r < 4; r++)
        Obuf[w][16 * qt + li][16 * mt + 4 * quad + r] = ot[mt][qt][r];
  if (quad == 0) {
    #pragma unroll
    for (int qt = 0; qt < 4; qt++) {
      Mbuf[w][qt][li] = m2[qt];
      Lbuf[w][qt][li] = lsum[qt];
    }
  }
  __syncthreads();

  // wave w handles qrows [16w, 16w+16); lane: row=li, cols quad*12..+11
  float M = Mbuf[0][w][li];
  #pragma unroll
  for (int sw = 1; sw < 4; sw++) M = fmaxf(M, Mbuf[sw][w][li]);
  float sc[4];
  float lt = 0.f;
  #pragma unroll
  for (int sw = 0; sw < 4; sw++) {
    sc[sw] = EXP2F(Mbuf[sw][w][li] - M);
    lt += Lbuf[sw][w][li] * sc[sw];
  }
  int orow = 16 * w + li;
  float* Obase = (z == 0) ? Opart0 : Opart1;
  float* Op = Obase + ((size_t)(head * 64 + qy) * 64 + orow) * 48 + quad * 12;
  #pragma unroll
  for (int g = 0; g < 3; g++) {
    float a0 = 0.f, a1 = 0.f, a2 = 0.f, a3 = 0.f;
    #pragma unroll
    for (int sw = 0; sw < 4; sw++) {
      const float* ob = &Obuf[sw][orow][quad * 12 + g * 4];
      a0 += ob[0] * sc[sw];
      a1 += ob[1] * sc[sw];
      a2 += ob[2] * sc[sw];
      a3 += ob[3] * sc[sw];
    }
    *(float4*)(Op + g * 4) = make_float4(a0, a1, a2, a3);
  }
  if (quad == 0) {
    size_t midx = ((size_t)(z * 8 + head) * 64 + qy) * 64 + orow;
    mpart[midx] = M;
    lpart[midx] = lt;
  }
}

// ---- combine the 2 KV-half partials, normalize, split to hi/lo ----
__global__ __launch_bounds__(256) void attn_merge_kernel(
    const float* __restrict__ Opart0, const float* __restrict__ Opart1,
    const float* __restrict__ mpart, const float* __restrict__ lpart,
    ushort* __restrict__ aoH, ushort* __restrict__ aoL)
{
  const int h = blockIdx.x, qt = blockIdx.y;
  const int tid = threadIdx.x;
  const int row = tid >> 2;
  const int cg = (tid & 3) * 12;
  const size_t tile = (size_t)h * 64 + qt;
  const size_t m0i = tile * 64 + row;
  const size_t m1i = (size_t)512 * 64 + m0i;
  float m0 = mpart[m0i], m1 = mpart[m1i];
  float l0 = lpart[m0i], l1 = lpart[m1i];
  float M = fmaxf(m0, m1);
  float s0 = EXP2F(m0 - M), s1 = EXP2F(m1 - M);
  float inv = 1.f / (l0 * s0 + l1 * s1);
  s0 *= inv; s1 *= inv;
  const float* O0 = Opart0 + (tile * 64 + row) * 48 + cg;
  const float* O1 = Opart1 + (tile * 64 + row) * 48 + cg;
  size_t outp = (size_t)(qt * 64 + row) * DIM + h * DH + cg;
  #pragma unroll
  for (int g = 0; g < 3; g++) {
    float4 a = *(const float4*)(O0 + g * 4);
    float4 b = *(const float4*)(O1 + g * 4);
    float v0 = a.x * s0 + b.x * s1;
    float v1 = a.y * s0 + b.y * s1;
    float v2 = a.z * s0 + b.z * s1;
    float v3 = a.w * s0 + b.w * s1;
    ushort4 H, L;
    bsplit(v0, H.x, L.x); bsplit(v1, H.y, L.y);
    bsplit(v2, H.z, L.z); bsplit(v3, H.w, L.w);
    *(ushort4*)(aoH + outp + g * 4) = H;
    *(ushort4*)(aoL + outp + g * 4) = L;
  }
}

// ======================= final projection + sigmoid =======================

__global__ __launch_bounds__(256) void out_kernel(const float* __restrict__ h,
    const float* __restrict__ Wout, const float* __restrict__ bout,
    float* __restrict__ out)
{
  int gw = (blockIdx.x * 256 + threadIdx.x) >> 6;
  int lane = threadIdx.x & 63;
  if (gw >= N_NODES) return;
  float s = 0.f;
  #pragma unroll
  for (int c = 0; c < 6; c++)
    s += h[(size_t)gw * DIM + lane + c * 64] * Wout[lane + c * 64];
  #pragma unroll
  for (int off = 32; off >= 1; off >>= 1) s += __shfl_xor(s, off, 64);
  if (lane == 0) out[gw] = 1.f / (1.f + __expf(-(s + bout[0])));
}

// ======================= launch =======================

extern "C" void kernel_launch(void* const* d_in, const int* in_sizes, int n_in,
                              void* d_out, int out_size, void* d_ws, size_t ws_size,
                              hipStream_t stream)
{
  const float* node_emb = (const float*)d_in[0];
  const int*   edge_index = (const int*)d_in[1];
  const float* W_conv = (const float*)d_in[2];
  const float* b_conv = (const float*)d_in[3];
  const float* W_in   = (const float*)d_in[4];
  const float* b_in   = (const float*)d_in[5];
  const float* W_ao   = (const float*)d_in[6];
  const float* b_ao   = (const float*)d_in[7];
  const float* W_out  = (const float*)d_in[8];
  const float* b_out  = (const float*)d_in[9];
  float* out = (float*)d_out;

  const size_t ND = (size_t)N_NODES * DIM;       // 1572864
  const size_t WI = (size_t)QKVD * DIM;          // 442368
  const size_t WC = (size_t)DIM * DIM;           // 147456

  float* h      = (float*)d_ws;
  ushort* aggH  = (ushort*)(h + ND);
  ushort* aggL  = aggH + ND;
  ushort* qhi   = aggL + ND;
  ushort* qlo   = qhi + ND;
  ushort* khi   = qlo + ND;
  ushort* klo   = khi + ND;
  ushort* vthi  = klo + ND;
  ushort* vtlo  = vthi + ND;
  ushort* aoH   = vtlo + ND;
  ushort* aoL   = aoH + ND;
  ushort* wiH   = aoL + ND;
  ushort* wiL   = wiH + WI;
  ushort* waoH  = wiL + WI;
  ushort* waoL  = waoH + WC;
  ushort* wctH  = waoL + WC;
  ushort* wctL  = wctH + 3 * WC;
  ushort* wfH   = wctL + 3 * WC;
  ushort* wfL   = wfH + 3 * WI;
  float* wibc   = (float*)(wfL + 3 * WI);
  float* Opart1 = wibc + 3 * QKVD;               // 8*64*64*48 = 1572864 floats
  float* mpart  = Opart1 + ND;                   // 2*8*64*64 = 65536
  float* lpart  = mpart + 65536;
  int* counts   = (int*)(lpart + 65536);
  int* offsets  = counts + N_NODES;
  int* cursor   = offsets + N_NODES + 1;
  int* ssrc     = cursor + N_NODES;

  // z=0 partials alias the agg hi/lo region (dead during attention: written by
  // aggregate, consumed by qkv_gemm, both strictly before attn in the stream).
  float* Opart0 = (float*)aggH;                  // ND floats

  const int* dst = edge_index;
  const int* src = edge_index + N_EDGES;

  // CSR build
  zero_counts_kernel<<<(N_NODES + 255) / 256, 256, 0, stream>>>(counts, cursor);
  count_kernel<<<N_EDGES / 256, 256, 0, stream>>>(dst, counts);
  scan_kernel<<<1, 1024, 0, stream>>>(counts, offsets);
  scatter_kernel<<<N_EDGES / 256, 256, 0, stream>>>(dst, src, offsets, cursor, ssrc);
  (void)hipMemcpyAsync(h, node_emb, ND * sizeof(float), hipMemcpyDeviceToDevice, stream);

  // weight prep
  transpose_split_kernel<<<dim3(12, 12, 3), dim3(32, 32), 0, stream>>>(W_conv, wctH, wctL);
  split_kernel<<<(int)(WI / 1024), 256, 0, stream>>>(W_in, wiH, wiL, (int)WI);
  split_kernel<<<(int)(WC / 1024), 256, 0, stream>>>(W_ao, waoH, waoL, (int)WC);
  wibc_kernel<<<864, 256, 0, stream>>>(W_in, b_conv, wibc);
  wprep_gemm<<<dim3(9, 3, 3), 256, 0, stream>>>(wiH, wiL, wctH, wctL, wfH, wfL);

  for (int l = 0; l < N_LAYERS; l++) {
    aggregate_kernel<<<N_NODES, 128, 0, stream>>>(h, ssrc, offsets, aggH, aggL);
    qkv_gemm<<<dim3(9, 32), 256, 0, stream>>>(
        wfH + (size_t)l * WI, wfL + (size_t)l * WI, aggH, aggL,
        wibc + (size_t)l * QKVD, b_in, counts,
        qhi, qlo, khi, klo, vthi, vtlo);
    attn_kernel<<<dim3(64, 8, 2), 256, 0, stream>>>(
        qhi, qlo, khi, klo, vthi, vtlo, Opart0, Opart1, mpart, lpart);
    attn_merge_kernel<<<dim3(8, 64), 256, 0, stream>>>(
        Opart0, Opart1, mpart, lpart, aoH, aoL);
    outproj_gemm<<<dim3(32, 3), 256, 0, stream>>>(
        aoH, aoL, waoH, waoL, b_ao, h);
  }
  out_kernel<<<1024, 256, 0, stream>>>(h, W_out, b_out, out);
}

// Round 10
// 778.244 us; speedup vs baseline: 1.5543x; 1.0154x over previous
//
#include <hip/hip_runtime.h>
#include <math.h>

#define N_NODES 4096
#define DIM 384
#define QKVD 1152
#define N_EDGES 131072
#define N_HEADS 8
#define DH 48
#define N_LAYERS 3

typedef short v4s __attribute__((ext_vector_type(4)));
typedef short v8s __attribute__((ext_vector_type(8)));
typedef float v4f __attribute__((ext_vector_type(4)));

#define MFMA32(A, B, C) __builtin_amdgcn_mfma_f32_16x16x32_bf16(A, B, C, 0, 0, 0)
#define MFMA16(A, B, C) __builtin_amdgcn_mfma_f32_16x16x16bf16_1k(A, B, C, 0, 0, 0)
#define EXP2F(x) __builtin_exp2f(x)

// ======================= CSR build (counting sort by dst) =======================

__global__ void zero_counts_kernel(int* counts, int* cursor) {
  int i = blockIdx.x * blockDim.x + threadIdx.x;
  if (i < N_NODES) { counts[i] = 0; cursor[i] = 0; }
}

__global__ void count_kernel(const int* __restrict__ dst, int* counts) {
  int e = blockIdx.x * blockDim.x + threadIdx.x;
  if (e < N_EDGES) atomicAdd(&counts[dst[e]], 1);
}

__global__ __launch_bounds__(1024) void scan_kernel(const int* __restrict__ counts,
                                                    int* __restrict__ offsets) {
  __shared__ int s[1024];
  int t = threadIdx.x;
  int base = t * 4;
  int c[4];
  int sum = 0;
  #pragma unroll
  for (int i = 0; i < 4; i++) { c[i] = counts[base + i]; sum += c[i]; }
  s[t] = sum;
  __syncthreads();
  for (int off = 1; off < 1024; off <<= 1) {
    int v = (t >= off) ? s[t - off] : 0;
    __syncthreads();
    s[t] += v;
    __syncthreads();
  }
  int excl = s[t] - sum;
  #pragma unroll
  for (int i = 0; i < 4; i++) { offsets[base + i] = excl; excl += c[i]; }
  if (t == 1023) offsets[N_NODES] = s[1023];
}

__global__ void scatter_kernel(const int* __restrict__ dst, const int* __restrict__ src,
                               const int* __restrict__ offsets, int* cursor,
                               int* __restrict__ ssrc) {
  int e = blockIdx.x * blockDim.x + threadIdx.x;
  if (e < N_EDGES) {
    int d = dst[e];
    int pos = atomicAdd(&cursor[d], 1);
    ssrc[offsets[d] + pos] = src[e];
  }
}

// ======================= bf16 split helpers =======================

__device__ __forceinline__ void bsplit(float v, ushort& hi, ushort& lo) {
  unsigned b = __float_as_uint(v);
  unsigned hb = b & 0xFFFF0000u;
  hi = (ushort)(b >> 16);
  float r = v - __uint_as_float(hb);
  lo = (ushort)(__float_as_uint(r) >> 16);
}

// pack hi16 of (a,b) into one dword (a in low half) — bf16 truncation
__device__ __forceinline__ unsigned pack2hi(float a, float b) {
  return __builtin_amdgcn_perm(__float_as_uint(b), __float_as_uint(a), 0x07060302u);
}

// ======================= neighbor aggregation (+ split epilogue) =================

__global__ __launch_bounds__(128) void aggregate_kernel(const float* __restrict__ h,
    const int* __restrict__ ssrc, const int* __restrict__ offsets,
    ushort* __restrict__ aggH, ushort* __restrict__ aggL) {
  int i = blockIdx.x;
  int t = threadIdx.x;
  int e0 = offsets[i], e1 = offsets[i + 1];
  float a0 = 0.f, a1 = 0.f, a2 = 0.f;
  int e = e0;
  for (; e + 2 <= e1; e += 2) {       // 2x unroll: 6 independent loads in flight
    const float* r0 = h + (size_t)ssrc[e] * DIM;
    const float* r1 = h + (size_t)ssrc[e + 1] * DIM;
    float x0 = r0[t], x1 = r0[t + 128], x2 = r0[t + 256];
    float y0 = r1[t], y1 = r1[t + 128], y2 = r1[t + 256];
    a0 += x0; a1 += x1; a2 += x2;
    a0 += y0; a1 += y1; a2 += y2;
  }
  if (e < e1) {
    const float* row = h + (size_t)ssrc[e] * DIM;
    a0 += row[t]; a1 += row[t + 128]; a2 += row[t + 256];
  }
  ushort h0, l0, h1, l1, h2, l2;
  bsplit(a0, h0, l0); bsplit(a1, h1, l1); bsplit(a2, h2, l2);
  size_t base = (size_t)i * DIM;
  aggH[base + t] = h0;       aggL[base + t] = l0;
  aggH[base + t + 128] = h1; aggL[base + t + 128] = l1;
  aggH[base + t + 256] = h2; aggL[base + t + 256] = l2;
}

// ======================= weight prep kernels =======================

__global__ void transpose_split_kernel(const float* __restrict__ Wc,
    ushort* __restrict__ wctH, ushort* __restrict__ wctL) {
  __shared__ float s[32][33];
  const int l = blockIdx.z;
  const float* W = Wc + (size_t)l * DIM * DIM;
  int tx = threadIdx.x, ty = threadIdx.y;
  s[ty][tx] = W[(size_t)(blockIdx.y * 32 + ty) * DIM + blockIdx.x * 32 + tx];
  __syncthreads();
  float v = s[tx][ty];
  ushort hi, lo;
  bsplit(v, hi, lo);
  size_t off = (size_t)l * DIM * DIM + (size_t)(blockIdx.x * 32 + ty) * DIM + blockIdx.y * 32 + tx;
  wctH[off] = hi;
  wctL[off] = lo;
}

__global__ void split_kernel(const float* __restrict__ src,
    ushort* __restrict__ hi, ushort* __restrict__ lo, int n) {
  int i = (blockIdx.x * 256 + threadIdx.x) * 4;
  if (i >= n) return;
  float4 v = *(const float4*)(src + i);
  ushort4 H, L;
  bsplit(v.x, H.x, L.x); bsplit(v.y, H.y, L.y);
  bsplit(v.z, H.z, L.z); bsplit(v.w, H.w, L.w);
  *(ushort4*)(hi + i) = H;
  *(ushort4*)(lo + i) = L;
}

// wibc[l][i] = dot(Wi[i,:], b_conv[l,:])
__global__ __launch_bounds__(256) void wibc_kernel(const float* __restrict__ Wi,
    const float* __restrict__ bconv, float* __restrict__ wibc) {
  int gw = (blockIdx.x * 256 + threadIdx.x) >> 6;
  int lane = threadIdx.x & 63;
  if (gw >= 3 * QKVD) return;
  int l = gw / QKVD, i = gw - l * QKVD;
  const float* w = Wi + (size_t)i * DIM;
  const float* b = bconv + (size_t)l * DIM;
  float s = 0.f;
  #pragma unroll
  for (int c = 0; c < 6; c++) s += w[lane + c * 64] * b[lane + c * 64];
  #pragma unroll
  for (int off = 32; off >= 1; off >>= 1) s += __shfl_xor(s, off, 64);
  if (lane == 0) wibc[gw] = s;
}

// ======================= split-bf16 MFMA GEMM core ==============================

template<int K>
__device__ __forceinline__ void mfma_core(
    const ushort* __restrict__ Ah, const ushort* __restrict__ Al,
    const ushort* __restrict__ Bh, const ushort* __restrict__ Bl,
    int aRow0, int bRow0, int li, int quad, v4f acc[4][4])
{
  for (int k0 = 0; k0 < K; k0 += 32) {
    v8s Afh[4], Afl[4], Bfh[4], Bfl[4];
    #pragma unroll
    for (int t = 0; t < 4; t++) {
      size_t ao = (size_t)(aRow0 + t * 16 + li) * K + k0 + quad * 8;
      size_t bo = (size_t)(bRow0 + t * 16 + li) * K + k0 + quad * 8;
      Afh[t] = *(const v8s*)(Ah + ao);
      Afl[t] = *(const v8s*)(Al + ao);
      Bfh[t] = *(const v8s*)(Bh + bo);
      Bfl[t] = *(const v8s*)(Bl + bo);
    }
    #pragma unroll
    for (int mt = 0; mt < 4; mt++)
      #pragma unroll
      for (int nt = 0; nt < 4; nt++) {
        v4f a = acc[mt][nt];
        a = MFMA32(Afh[mt], Bfh[nt], a);
        a = MFMA32(Afl[mt], Bfh[nt], a);
        a = MFMA32(Afh[mt], Bfl[nt], a);
        acc[mt][nt] = a;
      }
  }
}

// --- weight-prep GEMM: Wf[l] = Wi @ Wct[l] ---
__global__ __launch_bounds__(256) void wprep_gemm(
    const ushort* __restrict__ wiH, const ushort* __restrict__ wiL,
    const ushort* __restrict__ wctH, const ushort* __restrict__ wctL,
    ushort* __restrict__ wfH, ushort* __restrict__ wfL)
{
  const int l = blockIdx.z;
  const ushort* Bh = wctH + (size_t)l * DIM * DIM;
  const ushort* Bl = wctL + (size_t)l * DIM * DIM;
  ushort* oH = wfH + (size_t)l * QKVD * DIM;
  ushort* oL = wfL + (size_t)l * QKVD * DIM;
  const int tid = threadIdx.x;
  const int lane = tid & 63, li = lane & 15, quad = lane >> 4;
  const int w = tid >> 6, wm = w & 1, wn = w >> 1;
  const int aRow0 = blockIdx.x * 128 + wm * 64;
  const int bRow0 = blockIdx.y * 128 + wn * 64;
  v4f acc[4][4] = {};
  mfma_core<DIM>(wiH, wiL, Bh, Bl, aRow0, bRow0, li, quad, acc);
  #pragma unroll
  for (int mt = 0; mt < 4; mt++) {
    int i0 = aRow0 + mt * 16 + quad * 4;
    #pragma unroll
    for (int nt = 0; nt < 4; nt++) {
      int j = bRow0 + nt * 16 + li;
      #pragma unroll
      for (int r = 0; r < 4; r++) {
        ushort hi, lo;
        bsplit(acc[mt][nt][r], hi, lo);
        oH[(size_t)(i0 + r) * DIM + j] = hi;
        oL[(size_t)(i0 + r) * DIM + j] = lo;
      }
    }
  }
}

// --- fused qkv GEMM ---
__global__ __launch_bounds__(256) void qkv_gemm(
    const ushort* __restrict__ wfH, const ushort* __restrict__ wfL,
    const ushort* __restrict__ aggH, const ushort* __restrict__ aggL,
    const float* __restrict__ wibc_l, const float* __restrict__ b_in,
    const int* __restrict__ deg,
    ushort* __restrict__ qhi, ushort* __restrict__ qlo,
    ushort* __restrict__ khi, ushort* __restrict__ klo,
    ushort* __restrict__ vthi, ushort* __restrict__ vtlo)
{
  const int tid = threadIdx.x;
  const int lane = tid & 63, li = lane & 15, quad = lane >> 4;
  const int w = tid >> 6, wm = w & 1, wn = w >> 1;
  const int aRow0 = blockIdx.x * 128 + wm * 64;   // channel base
  const int bRow0 = blockIdx.y * 128 + wn * 64;   // node base
  v4f acc[4][4] = {};
  mfma_core<DIM>(wfH, wfL, aggH, aggL, aRow0, bRow0, li, quad, acc);

  const float cq = 0.20823507f;  // log2(e)/sqrt(48)
  int node[4]; float degf[4];
  #pragma unroll
  for (int nt = 0; nt < 4; nt++) {
    node[nt] = bRow0 + nt * 16 + li;
    degf[nt] = (float)deg[node[nt]];
  }
  #pragma unroll
  for (int mt = 0; mt < 4; mt++) {
    const int c0 = aRow0 + mt * 16 + quad * 4;
    const int part = c0 / DIM;
    const int cm = c0 - part * DIM;
    const int hd = cm / DH;
    const int d0 = cm - hd * DH;
    float wb[4], bb[4];
    #pragma unroll
    for (int r = 0; r < 4; r++) { wb[r] = wibc_l[c0 + r]; bb[r] = b_in[c0 + r]; }
    #pragma unroll
    for (int nt = 0; nt < 4; nt++) {
      float v0 = acc[mt][nt][0] + degf[nt] * wb[0] + bb[0];
      float v1 = acc[mt][nt][1] + degf[nt] * wb[1] + bb[1];
      float v2 = acc[mt][nt][2] + degf[nt] * wb[2] + bb[2];
      float v3 = acc[mt][nt][3] + degf[nt] * wb[3] + bb[3];
      if (part == 0) {
        v0 *= cq; v1 *= cq; v2 *= cq; v3 *= cq;
        ushort4 H, L;
        bsplit(v0, H.x, L.x); bsplit(v1, H.y, L.y);
        bsplit(v2, H.z, L.z); bsplit(v3, H.w, L.w);
        size_t off = ((size_t)hd * N_NODES + node[nt]) * DH + d0;
        *(ushort4*)(qhi + off) = H;
        *(ushort4*)(qlo + off) = L;
      } else if (part == 1) {
        ushort4 H, L;
        bsplit(v0, H.x, L.x); bsplit(v1, H.y, L.y);
        bsplit(v2, H.z, L.z); bsplit(v3, H.w, L.w);
        size_t off = ((size_t)hd * N_NODES + node[nt]) * DH + d0;
        *(ushort4*)(khi + off) = H;
        *(ushort4*)(klo + off) = L;
      } else {
        float vv[4] = {v0, v1, v2, v3};
        #pragma unroll
        for (int r = 0; r < 4; r++) {
          ushort hi, lo;
          bsplit(vv[r], hi, lo);
          size_t off = ((size_t)hd * DH + d0 + r) * N_NODES + node[nt];
          vthi[off] = hi;
          vtlo[off] = lo;
        }
      }
    }
  }
}

// --- attn-out GEMM: h = relu(ao @ Wao^T + b_ao + h) ---
__global__ __launch_bounds__(256) void outproj_gemm(
    const ushort* __restrict__ aoH, const ushort* __restrict__ aoL,
    const ushort* __restrict__ waoH, const ushort* __restrict__ waoL,
    const float* __restrict__ b_ao, float* __restrict__ h)
{
  const int tid = threadIdx.x;
  const int lane = tid & 63, li = lane & 15, quad = lane >> 4;
  const int w = tid >> 6, wm = w & 1, wn = w >> 1;
  const int aRow0 = blockIdx.x * 128 + wm * 64;   // node base
  const int bRow0 = blockIdx.y * 128 + wn * 64;   // channel base
  v4f acc[4][4] = {};
  mfma_core<DIM>(aoH, aoL, waoH, waoL, aRow0, bRow0, li, quad, acc);
  #pragma unroll
  for (int mt = 0; mt < 4; mt++) {
    int m0 = aRow0 + mt * 16 + quad * 4;
    #pragma unroll
    for (int nt = 0; nt < 4; nt++) {
      int n = bRow0 + nt * 16 + li;
      float ba = b_ao[n];
      #pragma unroll
      for (int r = 0; r < 4; r++) {
        size_t off = (size_t)(m0 + r) * DIM + n;
        float v = acc[mt][nt][r] + ba + h[off];
        h[off] = fmaxf(v, 0.f);
      }
    }
  }
}

// ======================= MFMA flash attention (split-bf16, KV-split 2) ==========
// grid (N/64=64, H=8, 2 KV-halves); consecutive block ids share head+z (R9
// swizzle: L3-speed K/V refills). 256 thr = 4 waves; wave w owns kcols
// [kb+16w, +16). bounds(256,2) (VGPR steps at 128 — R5). Guarded rescale
// (R8, exact): base m2 moves only when tile max exceeds m2+40.
// R10: bf16-P in PV — P truncated to bf16 (pack2hi), PV = Vh*P + Vl*P (V stays
// fp32-split-exact; only P residual dropped, standard flash-attn practice).
// Cuts PV MFMA 36->24/tile and deletes Pl psplit VALU. S-phase stays 3-term.

__global__ __launch_bounds__(256, 2) void attn_kernel(
    const ushort* __restrict__ qhi, const ushort* __restrict__ qlo,
    const ushort* __restrict__ khi, const ushort* __restrict__ klo,
    const ushort* __restrict__ vthi, const ushort* __restrict__ vtlo,
    float* __restrict__ Opart0, float* __restrict__ Opart1,
    float* __restrict__ mpart, float* __restrict__ lpart)
{
  const int head = blockIdx.y;
  const int qy = blockIdx.x;
  const int z = blockIdx.z;
  const int qBase = qy * 64;
  const int kb0 = z * (N_NODES / 2);
  const int tid = threadIdx.x;
  const int w = tid >> 6;
  const int lane = tid & 63;
  const int li = lane & 15, quad = lane >> 4;

  const size_t headQK = (size_t)head * N_NODES * DH;
  const size_t headV  = (size_t)head * DH * N_NODES;

  // resident Q fragments (4 q-tiles of 16 rows)
  v8s q0h[4], q0l[4];
  v4s q1h[4], q1l[4];
  #pragma unroll
  for (int qt = 0; qt < 4; qt++) {
    const ushort* qr = qhi + headQK + (size_t)(qBase + 16 * qt + li) * DH;
    const ushort* ql = qlo + headQK + (size_t)(qBase + 16 * qt + li) * DH;
    q0h[qt] = *(const v8s*)(qr + quad * 8);
    q0l[qt] = *(const v8s*)(ql + quad * 8);
    q1h[qt] = *(const v4s*)(qr + 32 + quad * 4);
    q1l[qt] = *(const v4s*)(ql + 32 + quad * 4);
  }

  v4f ot[3][4];
  #pragma unroll
  for (int mt = 0; mt < 3; mt++)
    #pragma unroll
    for (int qt = 0; qt < 4; qt++)
      ot[mt][qt] = (v4f){0.f, 0.f, 0.f, 0.f};
  float m2[4] = {-3.0e38f, -3.0e38f, -3.0e38f, -3.0e38f};
  float lsum[4] = {0.f, 0.f, 0.f, 0.f};

  const ushort* kh0 = khi + headQK + (size_t)(kb0 + 16 * w + li) * DH;
  const ushort* kl0 = klo + headQK + (size_t)(kb0 + 16 * w + li) * DH;
  const ushort* vh0 = vthi + headV + (size_t)li * N_NODES + kb0 + 16 * w + quad * 4;
  const ushort* vl0 = vtlo + headV + (size_t)li * N_NODES + kb0 + 16 * w + quad * 4;

  struct KV { v8s k0h, k0l; v4s k1h, k1l; v4s vh[3], vl[3]; };
  KV A, B;

  auto load_tile = [&](int t, KV& T) {
    const ushort* kh = kh0 + (size_t)t * (64 * DH);
    const ushort* kl = kl0 + (size_t)t * (64 * DH);
    T.k0h = *(const v8s*)(kh + quad * 8);
    T.k0l = *(const v8s*)(kl + quad * 8);
    T.k1h = *(const v4s*)(kh + 32 + quad * 4);
    T.k1l = *(const v4s*)(kl + 32 + quad * 4);
    const ushort* vh = vh0 + t * 64;
    const ushort* vl = vl0 + t * 64;
    #pragma unroll
    for (int mt = 0; mt < 3; mt++) {
      T.vh[mt] = *(const v4s*)(vh + (size_t)mt * (16 * N_NODES));
      T.vl[mt] = *(const v4s*)(vl + (size_t)mt * (16 * N_NODES));
    }
  };

  auto proc_tile = [&](const KV& T) {
    // S^T = K·Q^T (log2-domain scores via pre-scaled q) — 3-term exact
    v4f s[4];
    #pragma unroll
    for (int qt = 0; qt < 4; qt++) {
      v4f acc = (v4f){0.f, 0.f, 0.f, 0.f};
      acc = MFMA32(T.k0h, q0h[qt], acc);
      acc = MFMA32(T.k0l, q0h[qt], acc);
      acc = MFMA32(T.k0h, q0l[qt], acc);
      acc = MFMA16(T.k1h, q1h[qt], acc);
      acc = MFMA16(T.k1l, q1h[qt], acc);
      acc = MFMA16(T.k1h, q1l[qt], acc);
      s[qt] = acc;
    }

    // guarded-base softmax: rescale only when tile max exceeds m2+40 (rare)
    v4s pH[4];
    #pragma unroll
    for (int qt = 0; qt < 4; qt++) {
      float mx = fmaxf(fmaxf(s[qt][0], s[qt][1]), fmaxf(s[qt][2], s[qt][3]));
      if (__any(mx > m2[qt] + 40.f)) {          // wave-uniform branch
        float mr = fmaxf(mx, __shfl_xor(mx, 16, 64));
        mr = fmaxf(mr, __shfl_xor(mr, 32, 64)); // row-uniform new max
        float mn = fmaxf(m2[qt], mr);
        float a = EXP2F(m2[qt] - mn);           // 0 on first tile
        m2[qt] = mn;
        lsum[qt] *= a;
        #pragma unroll
        for (int mt = 0; mt < 3; mt++) ot[mt][qt] *= a;
      }
      float p0 = EXP2F(s[qt][0] - m2[qt]);      // bounded <= 2^40
      float p1 = EXP2F(s[qt][1] - m2[qt]);
      float p2 = EXP2F(s[qt][2] - m2[qt]);
      float p3 = EXP2F(s[qt][3] - m2[qt]);
      lsum[qt] += (p0 + p1) + (p2 + p3);
      union { uint2 u; v4s v; } uh;
      uh.u = make_uint2(pack2hi(p0, p1), pack2hi(p2, p3));
      pH[qt] = uh.v;
    }

    // O^T += V^T · P^T  (bf16 P, fp32-split V)
    #pragma unroll
    for (int mt = 0; mt < 3; mt++) {
      #pragma unroll
      for (int qt = 0; qt < 4; qt++) {
        v4f acc = ot[mt][qt];
        acc = MFMA16(T.vh[mt], pH[qt], acc);
        acc = MFMA16(T.vl[mt], pH[qt], acc);
        ot[mt][qt] = acc;
      }
    }
  };

  load_tile(0, A);
  for (int it = 0; it < 32; it += 2) {
    load_tile(it + 1, B);
    proc_tile(A);
    load_tile(it + 2, A);   // it=30 prefetches tile 32: overrun lands in
                            // adjacent mapped ws buffers, values never consumed
    proc_tile(B);
  }

  // finish deferred lsum: reduce across quads (m2 row-uniform -> consistent)
  #pragma unroll
  for (int qt = 0; qt < 4; qt++) {
    lsum[qt] += __shfl_xor(lsum[qt], 16, 64);
    lsum[qt] += __shfl_xor(lsum[qt], 32, 64);
  }

  // ---- merge the 4 per-wave partials (block-local), write unnormalized ----
  __shared__ float Obuf[4][64][49];
  __shared__ float Mbuf[4][4][16];
  __shared__ float Lbuf[4][4][16];

  #pragma unroll
  for (int mt = 0; mt < 3; mt++)
    #pragma unroll
    for (int qt = 0; qt < 4; qt++)
      #pragma unroll
      for (int r = 0; r < 4; r++)
        Obuf[w][16 * qt + li][16 * mt + 4 * quad + r] = ot[mt][qt][r];
  if (quad == 0) {
    #pragma unroll
    for (int qt = 0; qt < 4; qt++) {
      Mbuf[w][qt][li] = m2[qt];
      Lbuf[w][qt][li] = lsum[qt];
    }
  }
  __syncthreads();

  // wave w handles qrows [16w, 16w+16); lane: row=li, cols quad*12..+11
  float M = Mbuf[0][w][li];
  #pragma unroll
  for (int sw = 1; sw < 4; sw++) M = fmaxf(M, Mbuf[sw][w][li]);
  float sc[4];
  float lt = 0.f;
  #pragma unroll
  for (int sw = 0; sw < 4; sw++) {
    sc[sw] = EXP2F(Mbuf[sw][w][li] - M);
    lt += Lbuf[sw][w][li] * sc[sw];
  }
  int orow = 16 * w + li;
  float* Obase = (z == 0) ? Opart0 : Opart1;
  float* Op = Obase + ((size_t)(head * 64 + qy) * 64 + orow) * 48 + quad * 12;
  #pragma unroll
  for (int g = 0; g < 3; g++) {
    float a0 = 0.f, a1 = 0.f, a2 = 0.f, a3 = 0.f;
    #pragma unroll
    for (int sw = 0; sw < 4; sw++) {
      const float* ob = &Obuf[sw][orow][quad * 12 + g * 4];
      a0 += ob[0] * sc[sw];
      a1 += ob[1] * sc[sw];
      a2 += ob[2] * sc[sw];
      a3 += ob[3] * sc[sw];
    }
    *(float4*)(Op + g * 4) = make_float4(a0, a1, a2, a3);
  }
  if (quad == 0) {
    size_t midx = ((size_t)(z * 8 + head) * 64 + qy) * 64 + orow;
    mpart[midx] = M;
    lpart[midx] = lt;
  }
}

// ---- combine the 2 KV-half partials, normalize, split to hi/lo ----
__global__ __launch_bounds__(256) void attn_merge_kernel(
    const float* __restrict__ Opart0, const float* __restrict__ Opart1,
    const float* __restrict__ mpart, const float* __restrict__ lpart,
    ushort* __restrict__ aoH, ushort* __restrict__ aoL)
{
  const int h = blockIdx.x, qt = blockIdx.y;
  const int tid = threadIdx.x;
  const int row = tid >> 2;
  const int cg = (tid & 3) * 12;
  const size_t tile = (size_t)h * 64 + qt;
  const size_t m0i = tile * 64 + row;
  const size_t m1i = (size_t)512 * 64 + m0i;
  float m0 = mpart[m0i], m1 = mpart[m1i];
  float l0 = lpart[m0i], l1 = lpart[m1i];
  float M = fmaxf(m0, m1);
  float s0 = EXP2F(m0 - M), s1 = EXP2F(m1 - M);
  float inv = 1.f / (l0 * s0 + l1 * s1);
  s0 *= inv; s1 *= inv;
  const float* O0 = Opart0 + (tile * 64 + row) * 48 + cg;
  const float* O1 = Opart1 + (tile * 64 + row) * 48 + cg;
  size_t outp = (size_t)(qt * 64 + row) * DIM + h * DH + cg;
  #pragma unroll
  for (int g = 0; g < 3; g++) {
    float4 a = *(const float4*)(O0 + g * 4);
    float4 b = *(const float4*)(O1 + g * 4);
    float v0 = a.x * s0 + b.x * s1;
    float v1 = a.y * s0 + b.y * s1;
    float v2 = a.z * s0 + b.z * s1;
    float v3 = a.w * s0 + b.w * s1;
    ushort4 H, L;
    bsplit(v0, H.x, L.x); bsplit(v1, H.y, L.y);
    bsplit(v2, H.z, L.z); bsplit(v3, H.w, L.w);
    *(ushort4*)(aoH + outp + g * 4) = H;
    *(ushort4*)(aoL + outp + g * 4) = L;
  }
}

// ======================= final projection + sigmoid =======================

__global__ __launch_bounds__(256) void out_kernel(const float* __restrict__ h,
    const float* __restrict__ Wout, const float* __restrict__ bout,
    float* __restrict__ out)
{
  int gw = (blockIdx.x * 256 + threadIdx.x) >> 6;
  int lane = threadIdx.x & 63;
  if (gw >= N_NODES) return;
  float s = 0.f;
  #pragma unroll
  for (int c = 0; c < 6; c++)
    s += h[(size_t)gw * DIM + lane + c * 64] * Wout[lane + c * 64];
  #pragma unroll
  for (int off = 32; off >= 1; off >>= 1) s += __shfl_xor(s, off, 64);
  if (lane == 0) out[gw] = 1.f / (1.f + __expf(-(s + bout[0])));
}

// ======================= launch =======================

extern "C" void kernel_launch(void* const* d_in, const int* in_sizes, int n_in,
                              void* d_out, int out_size, void* d_ws, size_t ws_size,
                              hipStream_t stream)
{
  const float* node_emb = (const float*)d_in[0];
  const int*   edge_index = (const int*)d_in[1];
  const float* W_conv = (const float*)d_in[2];
  const float* b_conv = (const float*)d_in[3];
  const float* W_in   = (const float*)d_in[4];
  const float* b_in   = (const float*)d_in[5];
  const float* W_ao   = (const float*)d_in[6];
  const float* b_ao   = (const float*)d_in[7];
  const float* W_out  = (const float*)d_in[8];
  const float* b_out  = (const float*)d_in[9];
  float* out = (float*)d_out;

  const size_t ND = (size_t)N_NODES * DIM;       // 1572864
  const size_t WI = (size_t)QKVD * DIM;          // 442368
  const size_t WC = (size_t)DIM * DIM;           // 147456

  float* h      = (float*)d_ws;
  ushort* aggH  = (ushort*)(h + ND);
  ushort* aggL  = aggH + ND;
  ushort* qhi   = aggL + ND;
  ushort* qlo   = qhi + ND;
  ushort* khi   = qlo + ND;
  ushort* klo   = khi + ND;
  ushort* vthi  = klo + ND;
  ushort* vtlo  = vthi + ND;
  ushort* aoH   = vtlo + ND;
  ushort* aoL   = aoH + ND;
  ushort* wiH   = aoL + ND;
  ushort* wiL   = wiH + WI;
  ushort* waoH  = wiL + WI;
  ushort* waoL  = waoH + WC;
  ushort* wctH  = waoL + WC;
  ushort* wctL  = wctH + 3 * WC;
  ushort* wfH   = wctL + 3 * WC;
  ushort* wfL   = wfH + 3 * WI;
  float* wibc   = (float*)(wfL + 3 * WI);
  float* Opart1 = wibc + 3 * QKVD;               // 8*64*64*48 = 1572864 floats
  float* mpart  = Opart1 + ND;                   // 2*8*64*64 = 65536
  float* lpart  = mpart + 65536;
  int* counts   = (int*)(lpart + 65536);
  int* offsets  = counts + N_NODES;
  int* cursor   = offsets + N_NODES + 1;
  int* ssrc     = cursor + N_NODES;

  // z=0 partials alias the agg hi/lo region (dead during attention: written by
  // aggregate, consumed by qkv_gemm, both strictly before attn in the stream).
  float* Opart0 = (float*)aggH;                  // ND floats

  const int* dst = edge_index;
  const int* src = edge_index + N_EDGES;

  // CSR build
  zero_counts_kernel<<<(N_NODES + 255) / 256, 256, 0, stream>>>(counts, cursor);
  count_kernel<<<N_EDGES / 256, 256, 0, stream>>>(dst, counts);
  scan_kernel<<<1, 1024, 0, stream>>>(counts, offsets);
  scatter_kernel<<<N_EDGES / 256, 256, 0, stream>>>(dst, src, offsets, cursor, ssrc);
  (void)hipMemcpyAsync(h, node_emb, ND * sizeof(float), hipMemcpyDeviceToDevice, stream);

  // weight prep
  transpose_split_kernel<<<dim3(12, 12, 3), dim3(32, 32), 0, stream>>>(W_conv, wctH, wctL);
  split_kernel<<<(int)(WI / 1024), 256, 0, stream>>>(W_in, wiH, wiL, (int)WI);
  split_kernel<<<(int)(WC / 1024), 256, 0, stream>>>(W_ao, waoH, waoL, (int)WC);
  wibc_kernel<<<864, 256, 0, stream>>>(W_in, b_conv, wibc);
  wprep_gemm<<<dim3(9, 3, 3), 256, 0, stream>>>(wiH, wiL, wctH, wctL, wfH, wfL);

  for (int l = 0; l < N_LAYERS; l++) {
    aggregate_kernel<<<N_NODES, 128, 0, stream>>>(h, ssrc, offsets, aggH, aggL);
    qkv_gemm<<<dim3(9, 32), 256, 0, stream>>>(
        wfH + (size_t)l * WI, wfL + (size_t)l * WI, aggH, aggL,
        wibc + (size_t)l * QKVD, b_in, counts,
        qhi, qlo, khi, klo, vthi, vtlo);
    attn_kernel<<<dim3(64, 8, 2), 256, 0, stream>>>(
        qhi, qlo, khi, klo, vthi, vtlo, Opart0, Opart1, mpart, lpart);
    attn_merge_kernel<<<dim3(8, 64), 256, 0, stream>>>(
        Opart0, Opart1, mpart, lpart, aoH, aoL);
    outproj_gemm<<<dim3(32, 3), 256, 0, stream>>>(
        aoH, aoL, waoH, waoL, b_ao, h);
  }
  out_kernel<<<1024, 256, 0, stream>>>(h, W_out, b_out, out);
}